// Round 9
// baseline (618.738 us; speedup 1.0000x reference)
//
#include <hip/hip_runtime.h>
#include <math.h>

#define NB 2
#define NPTS 8192
#define CH 128
#define KNN 16
#define K17 17
#define EPSI 1e-5f
#define SLOPE 0.2f
#define NCH 32        // filter chunks
#define CHSZ 256      // candidates per chunk
#define SCAP 8        // survivor cap per chunk (round-9: 16->8 so surv fits uv region;
                      // overflow -> exact inline rescan in mergeB, correctness unchanged)
#define BIGF 3.0e38f

// ---------------- workspace layout (bytes) ----------------
// idx  [B][N][16] int            @ 0            (1 MB)
// x0b  [B][N][128] f32           @ 1,048,576    (8 MB)
// ym1  [B][N][128] f32           @ 9,437,184    (8 MB)
// ym2  [B][N][256] f32           @ 17,825,792   (16 MB)  } stage-2 uv2 lives here in KNN->edge2 window
// uv   [B][N][512] f32           @ 34,603,008   (32 MB)  } KNN phase: surv [B][N][32][8] float2 (exactly 32MB)
//                                                         } stage-4: y4b partial (8MB)
// y4   [B][N][128] f32           @ 68,157,440   (8 MB)   } pa aliases y4
// counts [B][N][32] int          @ 76,546,048   (2 MB)
// tau                            @ 78,643,200   (64 KB)
// Wm1 [256][128]                 @ 78,708,736
// Wm2 [512][128]                 @ 78,839,808
// stats (2048 f32)               @ 79,101,952
// scb1 [B][128] float2           @ 79,110,144
// scb2 [B][256] float2           @ 79,112,192
// pts4 [B][N] float4             @ 79,116,288
#define OFF_IDX   0L
#define OFF_X0B   1048576L
#define OFF_YM1   9437184L
#define OFF_YM2   17825792L
#define OFF_UV    34603008L
#define OFF_Y4    68157440L
#define OFF_SURV  OFF_UV
#define OFF_PA    OFF_Y4
#define OFF_CNT   76546048L
#define OFF_TAU   78643200L
#define OFF_WM1   78708736L
#define OFF_WM2   78839808L
#define OFF_STATS 79101952L
#define OFF_SCB1  79110144L
#define OFF_SCB2  79112192L
#define OFF_PTS4  79116288L

// ---------------- small utility kernels ----------------

__global__ void zero_stats_k(float* __restrict__ stats) {
  int t = blockIdx.x * 256 + threadIdx.x;
  if (t < 2048) stats[t] = 0.f;
}

// sums (sum, sumsq) -> (scale, bias) per (b, col):  z = y*scale + bias
__global__ void finalize_scb_k(const float* __restrict__ stats, float2* __restrict__ scb,
                               int count, float cinv) {
  int t = blockIdx.x * 256 + threadIdx.x;
  if (t < count) {
    float mean = stats[t * 2] * cinv;
    float var = stats[t * 2 + 1] * cinv - mean * mean;
    float inv = rsqrtf(var + EPSI);
    scb[t] = make_float2(inv, -mean * inv);
  }
}

// ---------------- KNN ----------------
__global__ void knn_prep_k(const float* __restrict__ coords, float4* __restrict__ pts) {
  int b = blockIdx.y;
  int i = blockIdx.x * 256 + threadIdx.x;
  const float* cb = coords + (long)b * 3 * NPTS;
  float x = cb[i], y = cb[NPTS + i], z = cb[2 * NPTS + i];
  float sq = __fadd_rn(__fadd_rn(__fmul_rn(x, x), __fmul_rn(y, y)), __fmul_rn(z, z));
  pts[(long)b * NPTS + i] = make_float4(x, y, z, sq);
}

#define DIST(pi, pj, d2)                                                          \
  float dot = __fadd_rn(__fadd_rn(__fmul_rn((pi).x, (pj).x), __fmul_rn((pi).y, (pj).y)), \
                        __fmul_rn((pi).z, (pj).z));                               \
  float d2 = __fsub_rn(__fadd_rn((pi).w, (pj).w), __fmul_rn(2.0f, dot));

// Stable predicated insertion into ascending (d, id) list; ties keep earlier insert.
#define KNN_INSERT(d2v, jv)                                              \
  if ((d2v) < d[K17 - 1]) {                                              \
    _Pragma("unroll")                                                    \
    for (int s = K17 - 1; s > 0; --s) {                                  \
      if ((d2v) < d[s - 1]) { d[s] = d[s - 1]; id[s] = id[s - 1]; }      \
      else if ((d2v) < d[s]) { d[s] = (d2v); id[s] = (jv); }             \
    }                                                                    \
    if ((d2v) < d[0]) { d[0] = (d2v); id[0] = (jv); }                    \
  }

// Phase A: 32 sub-threads per point; sub s keeps top-2 of sample candidates
// j in [s*64, s*64+64) (sample = first 2048 points).
__global__ __launch_bounds__(256) void knn_phaseA_k(const float4* __restrict__ pts,
                                                    float2* __restrict__ pa) {
  int b = blockIdx.y;
  int ib = blockIdx.x & 127;
  int sg = blockIdx.x >> 7;          // 0..7
  int i = ib * 64 + (threadIdx.x & 63);
  int sub = sg * 4 + (threadIdx.x >> 6);   // 0..31
  const float4* P = pts + (long)b * NPTS;
  float4 pi = P[i];
  float d0 = BIGF, d1 = BIGF;
  int i0 = 0x7fffffff, i1 = 0x7fffffff;
  int j0 = sub * 64;
  for (int jj = 0; jj < 64; ++jj) {
    float4 pj = P[j0 + jj];
    DIST(pi, pj, d2)
    if (d2 < d1) {
      if (d2 < d0) { d1 = d0; i1 = i0; d0 = d2; i0 = j0 + jj; }
      else { d1 = d2; i1 = j0 + jj; }
    }
  }
  long base = (((long)b * NPTS + i) * 32 + sub) * 2;
  pa[base] = make_float2(d0, __int_as_float(i0));
  pa[base + 1] = make_float2(d1, __int_as_float(i1));
}

// Merge 32x2 partials -> tau = 17th smallest of the 64 sample distances
__global__ __launch_bounds__(256) void knn_mergeA_k(const float2* __restrict__ pa,
                                                    float* __restrict__ tau) {
  int b = blockIdx.y;
  int i = blockIdx.x * 256 + threadIdx.x;
  float d[K17]; int id[K17];
#pragma unroll
  for (int s = 0; s < K17; ++s) { d[s] = BIGF; id[s] = 0x7fffffff; }
  long base = ((long)b * NPTS + i) * 64;
  for (int c = 0; c < 64; ++c) {
    float2 v = pa[base + c];
    if (v.x < d[K17 - 1]) {
      int j = __float_as_int(v.y);
      KNN_INSERT(v.x, j);
    }
  }
  tau[(long)b * NPTS + i] = d[K17 - 1];
}

// ---------------- FUSE1: knn_filter U transpose_x0 U prep_w (round 9) ---------
// Grid-union of three INDEPENDENT kernels so they co-schedule on the CUs
// (filter = VALU+L2-read heavy; transpose/prep = small). Disjoint writes:
// filter -> surv@uv + counts; transpose -> x0b; prep -> wm1/wm2.
// blocks [0,2048) filter | [2048,4096) transpose | [4096,4352) prep_w.
__global__ __launch_bounds__(256) void fuse1_k(const float4* __restrict__ pts,
                                               const float* __restrict__ tau,
                                               float2* __restrict__ surv,
                                               int* __restrict__ counts,
                                               const float* __restrict__ feat,
                                               float* __restrict__ x0b,
                                               const float* __restrict__ W1,
                                               const float* __restrict__ W2,
                                               float* __restrict__ Wm1,
                                               float* __restrict__ Wm2) {
  __shared__ float tile[32][33];
  int blk = blockIdx.x;
  int tid = threadIdx.x;
  if (blk < 2048) {
    // ---- knn_filter: per (i, chunk) thread, append candidates with d2 <= tau_i
    int b = blk >> 10;
    int chunk = (blk >> 5) & 31;
    int i = (blk & 31) * 256 + tid;
    const float4* P = pts + (long)b * NPTS;
    float4 pi = P[i];
    float t = tau[(long)b * NPTS + i];
    long sbase = (((long)b * NPTS + i) * NCH + chunk) * SCAP;
    int cnt = 0;
    int j0 = chunk * CHSZ;
#pragma unroll 2
    for (int jj = 0; jj < CHSZ; ++jj) {
      float4 pj = P[j0 + jj];
      DIST(pi, pj, d2)
      if (d2 <= t) {
        if (cnt < SCAP) surv[sbase + cnt] = make_float2(d2, __int_as_float(j0 + jj));
        cnt++;
      }
    }
    counts[((long)b * NPTS + i) * NCH + chunk] = cnt;
  } else if (blk < 4096) {
    // ---- transpose_x0: features [B][128][N] -> x0b[b][n][0:128]
    int tb = blk - 2048;
    int b = tb >> 10;
    int n0 = (tb & 255) * 32;
    int c0 = ((tb >> 8) & 3) * 32;
    int tx = tid & 31, ty0 = tid >> 5;
    for (int ty = ty0; ty < 32; ty += 8)
      tile[ty][tx] = feat[((long)b * CH + c0 + ty) * NPTS + n0 + tx];
    __syncthreads();
    for (int ty = ty0; ty < 32; ty += 8)
      x0b[((long)b * NPTS + n0 + ty) * 128 + c0 + tx] = tile[tx][ty];
  } else {
    // ---- prep_w: edge-decomposed weight transforms
    int t = (blk - 4096) * 256 + tid;
    if (t < 256 * 128) {
      int r = t >> 7, k = t & 127;
      Wm1[t] = (r < 128) ? (W1[r * 256 + k] - W1[r * 256 + 128 + k])
                         : W1[(r - 128) * 256 + 128 + k];
    }
    if (t < 512 * 128) {
      int r = t >> 7, k = t & 127;
      Wm2[t] = (r < 256) ? (W2[r * 256 + k] - W2[r * 256 + 128 + k])
                         : W2[(r - 256) * 256 + 128 + k];
    }
  }
}

// ---------------- FUSE2: knn_mergeB U gemm_xt(stage2) (round 9) ---------------
// INDEPENDENT: mergeB reads surv/counts/pts -> writes idx; gemm reads x0b/wm1
// (written by fuse1) -> writes uv2 (the ym2 region, dead until stage-3 edge).
// mergeB is gather/latency-heavy, gemm is LDS-heavy -> complementary pipes.
// blocks [0,512) mergeB | [512,1024) gemm. LDS union 34816B -> 4 blocks/CU.
#define GBN 128
#define GBM 64
#define GBK 32
__global__ __launch_bounds__(256) void fuse2_k(const float2* __restrict__ surv,
                                               const int* __restrict__ counts,
                                               const float4* __restrict__ pts,
                                               int* __restrict__ idxo,
                                               const float* __restrict__ x0b,
                                               const float* __restrict__ wm1,
                                               float* __restrict__ uv2) {
  __shared__ char smem[8 * K17 * 32 * 8];   // 34816 B (mergeB float2[8][17][32])
  int blk = blockIdx.x;
  int tid = threadIdx.x;
  if (blk < 512) {
    // ---- knn_mergeB: 32 points x 8 subs, register top-17, LDS merge tree ----
    float2* Lm = (float2*)smem;
#define LB(a, s, p) Lm[(((a) * K17) + (s)) * 32 + (p)]
    int b = blk >> 8;
    int pl = tid & 31;
    int sub = tid >> 5;
    int i = (blk & 255) * 32 + pl;
    const float4* P = pts + (long)b * NPTS;
    float4 pi = P[i];
    float d[K17]; int id[K17];
#pragma unroll
    for (int s = 0; s < K17; ++s) { d[s] = BIGF; id[s] = 0x7fffffff; }
    long cbase = ((long)b * NPTS + i) * NCH;
    int4 c4 = *(const int4*)(counts + cbase + sub * 4);
    int cnt4[4] = {c4.x, c4.y, c4.z, c4.w};
#pragma unroll
    for (int q = 0; q < 4; ++q) {
      int c = sub * 4 + q;
      int cnt = cnt4[q];
      if (cnt > SCAP) {
        // exact inline rescan of the overflowed chunk (same ascending-j order)
        int j0 = c * CHSZ;
        for (int jj = 0; jj < CHSZ; ++jj) {
          float4 pj = P[j0 + jj];
          DIST(pi, pj, d2)
          KNN_INSERT(d2, j0 + jj);
        }
      } else {
        long sb = (cbase + c) * SCAP;
        for (int p = 0; p < cnt; p += 2) {
          float4 v2 = *(const float4*)(surv + sb + p);
          if (v2.x < d[K17 - 1]) {
            int j = __float_as_int(v2.y);
            KNN_INSERT(v2.x, j);
          }
          if (p + 1 < cnt && v2.z < d[K17 - 1]) {
            int j = __float_as_int(v2.w);
            KNN_INSERT(v2.z, j);
          }
        }
      }
    }
#pragma unroll
    for (int s = 0; s < K17; ++s) LB(sub, s, pl) = make_float2(d[s], __int_as_float(id[s]));
    __syncthreads();
    if ((sub & 1) == 0) {
#pragma unroll
      for (int s = 0; s < K17; ++s) {
        float2 v = LB(sub + 1, s, pl);
        if (v.x < d[K17 - 1]) {
          int j = __float_as_int(v.y);
          KNN_INSERT(v.x, j);
        }
      }
    }
    __syncthreads();
    if ((sub & 1) == 0) {
#pragma unroll
      for (int s = 0; s < K17; ++s) LB(sub >> 1, s, pl) = make_float2(d[s], __int_as_float(id[s]));
    }
    __syncthreads();
    if (sub < 2) {
#pragma unroll
      for (int s = 0; s < K17; ++s) {
        float2 v = LB(2 * sub, s, pl);
        d[s] = v.x; id[s] = __float_as_int(v.y);
      }
#pragma unroll
      for (int s = 0; s < K17; ++s) {
        float2 v = LB(2 * sub + 1, s, pl);
        if (v.x < d[K17 - 1]) {
          int j = __float_as_int(v.y);
          KNN_INSERT(v.x, j);
        }
      }
    }
    __syncthreads();
    if (sub < 2) {
#pragma unroll
      for (int s = 0; s < K17; ++s) LB(sub, s, pl) = make_float2(d[s], __int_as_float(id[s]));
    }
    __syncthreads();
    if (sub == 0) {
#pragma unroll
      for (int s = 0; s < K17; ++s) {
        float2 v = LB(0, s, pl);
        d[s] = v.x; id[s] = __float_as_int(v.y);
      }
#pragma unroll
      for (int s = 0; s < K17; ++s) {
        float2 v = LB(1, s, pl);
        if (v.x < d[K17 - 1]) {
          int j = __float_as_int(v.y);
          KNN_INSERT(v.x, j);
        }
      }
      long ob = ((long)b * NPTS + i) * KNN;
#pragma unroll
      for (int s = 1; s < K17; ++s) idxo[ob + s - 1] = id[s];
    }
#undef LB
  } else {
    // ---- gemm_xt stage2: uv2[b][n][m] = sum_k x0b[b][n][k] * wm1[m][k] ----
    float (*Xs)[GBN + 4] = (float (*)[GBN + 4])smem;
    float (*Ws)[GBM + 4] = (float (*)[GBM + 4])(smem + sizeof(float) * GBK * (GBN + 4));
    int g = blk - 512;
    int b = g >> 8;
    int n0 = (g & 63) * GBN, m0 = ((g >> 6) & 3) * GBM;
    int tx = tid & 15, ty = tid >> 4;
    const float* Xb = x0b + (long)b * NPTS * 128;
    float* Ob = uv2 + (long)b * NPTS * 256;
    float acc[8][4];
#pragma unroll
    for (int i = 0; i < 8; ++i)
#pragma unroll
      for (int j = 0; j < 4; ++j) acc[i][j] = 0.f;

    for (int k0 = 0; k0 < 128; k0 += GBK) {
#pragma unroll
      for (int i = 0; i < 4; ++i) {
        int q = tid + i * 256;
        int r = q >> 3, kq = (q & 7) * 4;
        const float4 v = *(const float4*)(Xb + (long)(n0 + r) * 128 + k0 + kq);
        Xs[kq][r] = v.x; Xs[kq + 1][r] = v.y; Xs[kq + 2][r] = v.z; Xs[kq + 3][r] = v.w;
      }
#pragma unroll
      for (int i = 0; i < 2; ++i) {
        int q = tid + i * 256;
        int r = q >> 3, kq = (q & 7) * 4;
        const float4 v = *(const float4*)(wm1 + (long)(m0 + r) * 128 + k0 + kq);
        Ws[kq][r] = v.x; Ws[kq + 1][r] = v.y; Ws[kq + 2][r] = v.z; Ws[kq + 3][r] = v.w;
      }
      __syncthreads();
#pragma unroll
      for (int kk = 0; kk < GBK; ++kk) {
        float4 w4 = *(const float4*)&Ws[kk][tx * 4];
        float4 xa = *(const float4*)&Xs[kk][ty * 8];
        float4 xb4 = *(const float4*)&Xs[kk][ty * 8 + 4];
        float xs[8] = {xa.x, xa.y, xa.z, xa.w, xb4.x, xb4.y, xb4.z, xb4.w};
        float wv[4] = {w4.x, w4.y, w4.z, w4.w};
#pragma unroll
        for (int i = 0; i < 8; ++i)
#pragma unroll
          for (int j = 0; j < 4; ++j) acc[i][j] = fmaf(xs[i], wv[j], acc[i][j]);
      }
      __syncthreads();
    }
#pragma unroll
    for (int i = 0; i < 8; ++i) {
      float4 v = make_float4(acc[i][0], acc[i][1], acc[i][2], acc[i][3]);
      *(float4*)(Ob + (long)(n0 + ty * 8 + i) * 256 + m0 + tx * 4) = v;
    }
  }
}

#define AFFLK4(v, a0, a1, a2, a3)                              \
  v.x = fmaf(v.x, a0.x, a0.y); v.x = fmaxf(v.x, SLOPE * v.x);  \
  v.y = fmaf(v.y, a1.x, a1.y); v.y = fmaxf(v.y, SLOPE * v.y);  \
  v.z = fmaf(v.z, a2.x, a2.y); v.z = fmaxf(v.z, SLOPE * v.z);  \
  v.w = fmaf(v.w, a3.x, a3.y); v.w = fmaxf(v.w, SLOPE * v.w);

// stage-3 GEMM: X = leaky(affine(ym1)) applied during staging. K=128, X stride 128.
__global__ __launch_bounds__(256) void gemm_aff_k(const float* __restrict__ X,
                                                  const float2* __restrict__ scb,
                                                  const float* __restrict__ W,
                                                  float* __restrict__ Out, int so, long obs) {
  __shared__ float Xs[GBK][GBN + 4];
  __shared__ float Ws[GBK][GBM + 4];
  int b = blockIdx.z;
  const float* Xb = X + (long)b * NPTS * 128;
  const float2* sc = scb + b * 128;
  float* Ob = Out + (long)b * obs;
  int n0 = blockIdx.x * GBN, m0 = blockIdx.y * GBM;
  int tx = threadIdx.x, ty = threadIdx.y;
  int tid = ty * 16 + tx;
  float acc[8][4];
#pragma unroll
  for (int i = 0; i < 8; ++i)
#pragma unroll
    for (int j = 0; j < 4; ++j) acc[i][j] = 0.f;

  for (int k0 = 0; k0 < 128; k0 += GBK) {
#pragma unroll
    for (int i = 0; i < 4; ++i) {
      int q = tid + i * 256;
      int r = q >> 3, kq = (q & 7) * 4;
      float4 v = *(const float4*)(Xb + (long)(n0 + r) * 128 + k0 + kq);
      float2 a0 = sc[k0 + kq], a1 = sc[k0 + kq + 1], a2 = sc[k0 + kq + 2], a3 = sc[k0 + kq + 3];
      AFFLK4(v, a0, a1, a2, a3)
      Xs[kq][r] = v.x; Xs[kq + 1][r] = v.y; Xs[kq + 2][r] = v.z; Xs[kq + 3][r] = v.w;
    }
#pragma unroll
    for (int i = 0; i < 2; ++i) {
      int q = tid + i * 256;
      int r = q >> 3, kq = (q & 7) * 4;
      const float4 v = *(const float4*)(W + (long)(m0 + r) * 128 + k0 + kq);
      Ws[kq][r] = v.x; Ws[kq + 1][r] = v.y; Ws[kq + 2][r] = v.z; Ws[kq + 3][r] = v.w;
    }
    __syncthreads();
#pragma unroll
    for (int kk = 0; kk < GBK; ++kk) {
      float4 w4 = *(const float4*)&Ws[kk][tx * 4];
      float4 xa = *(const float4*)&Xs[kk][ty * 8];
      float4 xb4 = *(const float4*)&Xs[kk][ty * 8 + 4];
      float xs[8] = {xa.x, xa.y, xa.z, xa.w, xb4.x, xb4.y, xb4.z, xb4.w};
      float wv[4] = {w4.x, w4.y, w4.z, w4.w};
#pragma unroll
      for (int i = 0; i < 8; ++i)
#pragma unroll
        for (int j = 0; j < 4; ++j) acc[i][j] = fmaf(xs[i], wv[j], acc[i][j]);
    }
    __syncthreads();
  }
#pragma unroll
  for (int i = 0; i < 8; ++i) {
    float4 v = make_float4(acc[i][0], acc[i][1], acc[i][2], acc[i][3]);
    *(float4*)(Ob + (long)(n0 + ty * 8 + i) * so + m0 + tx * 4) = v;
  }
}

// stage-4 GEMM: 128n x 64m tile + split-K 2-way (round-7 proven: 512 blocks =
// 2 blocks/CU so staging/barriers of one block overlap compute of the other).
// k-half 0 = x0b + ym1; k-half 1 = ym2 (segment-aligned split).
__global__ __launch_bounds__(256) void gemm_cat_k(const float* __restrict__ x0b,
                                                  const float* __restrict__ ym1,
                                                  const float* __restrict__ ym2,
                                                  const float2* __restrict__ scb1,
                                                  const float2* __restrict__ scb2,
                                                  const float* __restrict__ W,
                                                  float* __restrict__ OutA,
                                                  float* __restrict__ OutB) {
  __shared__ float Xs[GBK][GBN + 4];
  __shared__ float Ws[GBK][GBM + 4];
  int b = blockIdx.z;
  int mt = blockIdx.y & 1;
  int kh = blockIdx.y >> 1;
  float* Ob = (kh ? OutB : OutA) + (long)b * NPTS * 128;
  int n0 = blockIdx.x * GBN, m0 = mt * GBM;
  int tx = threadIdx.x, ty = threadIdx.y;
  int tid = ty * 16 + tx;
  float acc[8][4];
#pragma unroll
  for (int i = 0; i < 8; ++i)
#pragma unroll
    for (int j = 0; j < 4; ++j) acc[i][j] = 0.f;

  for (int ks = 0; ks < 8; ++ks) {
    int k0 = kh * 256 + ks * GBK;
    const float* Xb; long st_; const float2* sc_; int cb_;
    if (k0 < 128)      { Xb = x0b + (long)b * NPTS * 128; st_ = 128; sc_ = nullptr;        cb_ = 0; }
    else if (k0 < 256) { Xb = ym1 + (long)b * NPTS * 128; st_ = 128; sc_ = scb1 + b * 128; cb_ = 128; }
    else               { Xb = ym2 + (long)b * NPTS * 256; st_ = 256; sc_ = scb2 + b * 256; cb_ = 256; }
    int kl = k0 - cb_;
#pragma unroll
    for (int i = 0; i < 4; ++i) {
      int q = tid + i * 256;
      int r = q >> 3, kq = (q & 7) * 4;
      float4 v = *(const float4*)(Xb + (long)(n0 + r) * st_ + kl + kq);
      if (sc_) {
        float2 a0 = sc_[kl + kq], a1 = sc_[kl + kq + 1], a2 = sc_[kl + kq + 2], a3 = sc_[kl + kq + 3];
        AFFLK4(v, a0, a1, a2, a3)
      }
      Xs[kq][r] = v.x; Xs[kq + 1][r] = v.y; Xs[kq + 2][r] = v.z; Xs[kq + 3][r] = v.w;
    }
#pragma unroll
    for (int i = 0; i < 2; ++i) {
      int q = tid + i * 256;
      int r = q >> 3, kq = (q & 7) * 4;
      const float4 v = *(const float4*)(W + (long)(m0 + r) * 512 + k0 + kq);
      Ws[kq][r] = v.x; Ws[kq + 1][r] = v.y; Ws[kq + 2][r] = v.z; Ws[kq + 3][r] = v.w;
    }
    __syncthreads();
#pragma unroll
    for (int kk = 0; kk < GBK; ++kk) {
      float4 w4 = *(const float4*)&Ws[kk][tx * 4];
      float4 xa = *(const float4*)&Xs[kk][ty * 8];
      float4 xb4 = *(const float4*)&Xs[kk][ty * 8 + 4];
      float xs[8] = {xa.x, xa.y, xa.z, xa.w, xb4.x, xb4.y, xb4.z, xb4.w};
      float wv[4] = {w4.x, w4.y, w4.z, w4.w};
#pragma unroll
      for (int i = 0; i < 8; ++i)
#pragma unroll
        for (int j = 0; j < 4; ++j) acc[i][j] = fmaf(xs[i], wv[j], acc[i][j]);
    }
    __syncthreads();
  }
#pragma unroll
  for (int i = 0; i < 8; ++i) {
    float4 v = make_float4(acc[i][0], acc[i][1], acc[i][2], acc[i][3]);
    *(float4*)(Ob + (long)(n0 + ty * 8 + i) * 128 + m0 + tx * 4) = v;
  }
}

// ---------------- edge (EXACT round-0 proven config, nt REVERTED) -------------
// y = u[n] + v[idx[n,k]]; max over k + channel sum/sumsq.
// LOAD-BEARING (measured A/B, do not perturb): PPB=32, 1024 blocks, (b,ct) in
// blk bits 1-2 -> per-XCD gather table 2-4 MB L2-resident; full residency
// (4 blocks/CU x 4 waves = 16 waves/CU, one wave-batch).
// Round-8 falsifier: nt hints cut FETCH 44->30MB with ZERO time change =>
// edge is NOT traffic-bound; nt stores hurt downstream readers. Reverted.
template <int CTILE, int PPB>
__global__ __launch_bounds__(256) void edge_max_t(const float* __restrict__ uv, int S, int voff,
                                                  int Cout, const int* __restrict__ idx,
                                                  float* __restrict__ ymax,
                                                  float* __restrict__ stats) {
  constexpr int CG = CTILE / 4;     // channel-groups (threads per point-row)
  constexpr int PSL = 256 / CG;     // point-slots per block
  __shared__ float ls[2][256][4];
  int blk = blockIdx.x;
  int c = (blk & 7) >> 1;           // combo 0..3
  int b = c >> 1;                   // batch
  int ct = c & 1;                   // channel tile
  int pblk = ((blk >> 3) << 1) | (blk & 1);
  int ch0 = ct * CTILE;
  const float* uvb = uv + (long)b * NPTS * S;
  const int* idxb = idx + (long)b * NPTS * KNN;
  float* ymb = ymax + (long)b * NPTS * Cout;
  int cg = threadIdx.x & (CG - 1);
  int ps = threadIdx.x / CG;
  int n0 = pblk * PPB;
  const float* vb = uvb + voff + ch0 + 4 * cg;
  float4 s = make_float4(0.f, 0.f, 0.f, 0.f);
  float4 s2 = make_float4(0.f, 0.f, 0.f, 0.f);
  for (int p = ps; p < PPB; p += PSL) {
    int n = n0 + p;
    const int* ip = idxb + n * KNN;
    int4 ia = *(const int4*)(ip);
    int4 ib4 = *(const int4*)(ip + 4);
    int4 ic = *(const int4*)(ip + 8);
    int4 id4 = *(const int4*)(ip + 12);
    int mi[KNN] = {ia.x, ia.y, ia.z, ia.w, ib4.x, ib4.y, ib4.z, ib4.w,
                   ic.x, ic.y, ic.z, ic.w, id4.x, id4.y, id4.z, id4.w};
    float4 u = *(const float4*)(uvb + (long)n * S + ch0 + 4 * cg);
    float4 mx = make_float4(-INFINITY, -INFINITY, -INFINITY, -INFINITY);
#pragma unroll
    for (int k = 0; k < KNN; ++k) {
      float4 v = *(const float4*)(vb + (long)mi[k] * S);
      float4 y;
      y.x = u.x + v.x; y.y = u.y + v.y; y.z = u.z + v.z; y.w = u.w + v.w;
      mx.x = fmaxf(mx.x, y.x); mx.y = fmaxf(mx.y, y.y);
      mx.z = fmaxf(mx.z, y.z); mx.w = fmaxf(mx.w, y.w);
      s.x += y.x; s.y += y.y; s.z += y.z; s.w += y.w;
      s2.x = fmaf(y.x, y.x, s2.x); s2.y = fmaf(y.y, y.y, s2.y);
      s2.z = fmaf(y.z, y.z, s2.z); s2.w = fmaf(y.w, y.w, s2.w);
    }
    *(float4*)(ymb + (long)n * Cout + ch0 + 4 * cg) = mx;
  }
  int t = threadIdx.x;
  ls[0][t][0] = s.x; ls[0][t][1] = s.y; ls[0][t][2] = s.z; ls[0][t][3] = s.w;
  ls[1][t][0] = s2.x; ls[1][t][1] = s2.y; ls[1][t][2] = s2.z; ls[1][t][3] = s2.w;
  __syncthreads();
  if (ps == 0) {
#pragma unroll
    for (int j = 1; j < PSL; ++j) {
      int q = j * CG + cg;
      s.x += ls[0][q][0]; s.y += ls[0][q][1]; s.z += ls[0][q][2]; s.w += ls[0][q][3];
      s2.x += ls[1][q][0]; s2.y += ls[1][q][1]; s2.z += ls[1][q][2]; s2.w += ls[1][q][3];
    }
    float* st = stats + ((long)b * Cout + ch0 + 4 * cg) * 2;
    atomicAdd(&st[0], s.x); atomicAdd(&st[1], s2.x);
    atomicAdd(&st[2], s.y); atomicAdd(&st[3], s2.y);
    atomicAdd(&st[4], s.z); atomicAdd(&st[5], s2.z);
    atomicAdd(&st[6], s.w); atomicAdd(&st[7], s2.w);
  }
}

// sum split-K halves -> y4; per-column (sum, sumsq) -> stats
__global__ void colstats2_k(float* __restrict__ y4, const float* __restrict__ y4b,
                            float* __restrict__ stats) {
  int b = blockIdx.y;
  int o = threadIdx.x & 127, slot = threadIdx.x >> 7;
  int n0 = blockIdx.x * 64;
  float s = 0.f, s2 = 0.f;
  for (int p = slot; p < 64; p += 2) {
    long off = ((long)b * NPTS + n0 + p) * 128 + o;
    float y = y4[off] + y4b[off];
    y4[off] = y;
    s += y;
    s2 = fmaf(y, y, s2);
  }
  float* st = stats + ((long)b * 128 + o) * 2;
  atomicAdd(&st[0], s);
  atomicAdd(&st[1], s2);
}

__global__ void final_k(const float* __restrict__ y3, const float* __restrict__ stats,
                        float* __restrict__ out) {
  __shared__ float tile[32][33];
  int b = blockIdx.z;
  int n0 = blockIdx.x * 32, o0 = blockIdx.y * 32;
  int tx = threadIdx.x;
  for (int ty = threadIdx.y; ty < 32; ty += 8) {
    int o = o0 + tx;
    const float* st = stats + ((long)b * 128 + o) * 2;
    float mean = st[0] * (1.f / 8192.f);
    float var = st[1] * (1.f / 8192.f) - mean * mean;
    float inv = rsqrtf(var + EPSI);
    float y = y3[((long)b * NPTS + n0 + ty) * 128 + o];
    float z = (y - mean) * inv;
    tile[ty][tx] = z >= 0.f ? z : SLOPE * z;
  }
  __syncthreads();
  for (int ty = threadIdx.y; ty < 32; ty += 8)
    out[((long)b * CH + o0 + ty) * NPTS + n0 + tx] = tile[tx][ty];
}

// ---------------- launch ----------------
extern "C" void kernel_launch(void* const* d_in, const int* in_sizes, int n_in,
                              void* d_out, int out_size, void* d_ws, size_t ws_size,
                              hipStream_t stream) {
  const float* coords = (const float*)d_in[0];
  const float* features = (const float*)d_in[1];
  const float* W1 = (const float*)d_in[2];
  const float* W2 = (const float*)d_in[3];
  const float* W3 = (const float*)d_in[4];
  float* out = (float*)d_out;
  char* ws = (char*)d_ws;

  int* idx = (int*)(ws + OFF_IDX);
  float* x0b = (float*)(ws + OFF_X0B);
  float* ym1 = (float*)(ws + OFF_YM1);
  float* ym2 = (float*)(ws + OFF_YM2);   // stage-2 uv2 during KNN->edge2 window
  float* uv = (float*)(ws + OFF_UV);
  float* y4 = (float*)(ws + OFF_Y4);
  float2* surv = (float2*)(ws + OFF_SURV);   // aliases uv (dead during KNN)
  float2* pa = (float2*)(ws + OFF_PA);
  int* counts = (int*)(ws + OFF_CNT);
  float* tau = (float*)(ws + OFF_TAU);
  float* wm1 = (float*)(ws + OFF_WM1);
  float* wm2 = (float*)(ws + OFF_WM2);
  float* stats = (float*)(ws + OFF_STATS);
  float2* scb1 = (float2*)(ws + OFF_SCB1);
  float2* scb2 = (float2*)(ws + OFF_SCB2);
  float4* pts4 = (float4*)(ws + OFF_PTS4);
  float* uv2 = ym2;

  zero_stats_k<<<8, 256, 0, stream>>>(stats);
  // ---- KNN front half ----
  knn_prep_k<<<dim3(NPTS / 256, NB), 256, 0, stream>>>(coords, pts4);
  knn_phaseA_k<<<dim3(1024, NB), 256, 0, stream>>>(pts4, pa);
  knn_mergeA_k<<<dim3(NPTS / 256, NB), 256, 0, stream>>>(pa, tau);
  // ---- FUSE1: filter U transpose U prep_w (independent, disjoint writes) ----
  fuse1_k<<<4352, 256, 0, stream>>>(pts4, tau, surv, counts, features, x0b, W1, W2, wm1,
                                    wm2);
  // ---- FUSE2: mergeB U gemm_xt(stage2 -> uv2@ym2 region) ----
  fuse2_k<<<1024, 256, 0, stream>>>(surv, counts, pts4, idx, x0b, wm1, uv2);
  // stage 2 edge (reads uv2, writes ym1)
  edge_max_t<64, 32><<<dim3(NPTS / 32 * 2 * NB), 256, 0, stream>>>(uv2, 256, 128, 128, idx,
                                                                   ym1, stats);
  finalize_scb_k<<<1, 256, 0, stream>>>(stats, scb1, 256, 1.0f / 131072.0f);
  // stage 3 (surv dead now; uv region free for gemm_aff output)
  gemm_aff_k<<<dim3(NPTS / GBN, 512 / GBM, NB), dim3(16, 16), 0, stream>>>(
      ym1, scb1, wm2, uv, 512, (long)NPTS * 512);
  edge_max_t<128, 32><<<dim3(NPTS / 32 * 2 * NB), 256, 0, stream>>>(uv, 512, 256, 256, idx,
                                                                    ym2, stats + 512);
  finalize_scb_k<<<2, 256, 0, stream>>>(stats + 512, scb2, 512, 1.0f / 131072.0f);
  // stage 4: 128x64 tile, split-K 2-way -> 512 blocks = 2/CU; partial B -> uv (dead)
  gemm_cat_k<<<dim3(NPTS / GBN, 4, NB), dim3(16, 16), 0, stream>>>(
      x0b, ym1, ym2, scb1, scb2, W3, y4, uv);
  colstats2_k<<<dim3(NPTS / 64, NB), 256, 0, stream>>>(y4, uv, stats + 1536);
  final_k<<<dim3(NPTS / 32, CH / 32, NB), dim3(32, 8), 0, stream>>>(y4, stats + 1536, out);
}

// Round 10
// 488.764 us; speedup vs baseline: 1.2659x; 1.2659x over previous
//
#include <hip/hip_runtime.h>
#include <math.h>

#define NB 2
#define NPTS 8192
#define CH 128
#define KNN 16
#define K17 17
#define EPSI 1e-5f
#define SLOPE 0.2f
#define NCH 32        // filter chunks
#define CHSZ 256      // candidates per chunk
#define SCAP 16       // survivor cap per chunk. LOAD-BEARING at 16: round-9 cut it
                      // to 8 (to alias surv into uv) and the overflow-rescan tail
                      // made the fused mergeB 230us (occupancy 11% = tail-bound).
#define BIGF 3.0e38f

// ---------------- workspace layout (bytes) ----------------
// idx  [B][N][16] int            @ 0            (1 MB)
// x0b  [B][N][128] f32           @ 1,048,576    (8 MB)   } surv aliases
// ym1  [B][N][128] f32           @ 9,437,184    (8 MB)
// ym2  [B][N][256] f32           @ 17,825,792   (16 MB)
// uv   [B][N][512] f32           @ 34,603,008   (32 MB)  } stage-4: y4b partial (8MB)
// y4   [B][N][128] f32           @ 68,157,440   (8 MB)   } pa aliases y4
// counts [B][N][32] int          @ 76,546,048   (2 MB)
// tau                            @ 78,643,200   (64 KB)
// Wm1 [256][128]                 @ 78,708,736
// Wm2 [512][128]                 @ 78,839,808
// stats (2048 f32)               @ 79,101,952
// scb1 [B][128] float2           @ 79,110,144
// scb2 [B][256] float2           @ 79,112,192
// pts4 [B][N] float4             @ 79,116,288
#define OFF_IDX   0L
#define OFF_X0B   1048576L
#define OFF_YM1   9437184L
#define OFF_YM2   17825792L
#define OFF_UV    34603008L
#define OFF_Y4    68157440L
#define OFF_SURV  OFF_X0B
#define OFF_PA    OFF_Y4
#define OFF_CNT   76546048L
#define OFF_TAU   78643200L
#define OFF_WM1   78708736L
#define OFF_WM2   78839808L
#define OFF_STATS 79101952L
#define OFF_SCB1  79110144L
#define OFF_SCB2  79112192L
#define OFF_PTS4  79116288L

// SESSION LEDGER (measured A/B, do not retry):
//  - edge kernel: 70us is a structural latency equilibrium. Survived: per-thread
//    MLP batching (v2: 3.6x WORSE), full-row gathers (v3: L2 thrash, 1.8x worse),
//    PPB=16 occupancy bump (r3: 114us), nt cache hints (r8: FETCH 44->30MB,
//    time UNCHANGED => not traffic-bound; nt stores hurt downstream).
//  - GEMMs: LDS-issue-bound (VALUBusy pinned ~22% across tilings). Row-dot
//    no-LDS form (r6): per-lane 512B address spread, +40us WORSE. 128x64 tile
//    + split-K 2/CU (r7) is the best stage-4 shape (74->~40us).
//  - Grid-union fusion of heterogeneous kernels (r9): tail-latency pathology,
//    fuse2 230us. Do not fuse.

// ---------------- small utility kernels ----------------

__global__ void zero_stats_k(float* __restrict__ stats) {
  int t = blockIdx.x * 256 + threadIdx.x;
  if (t < 2048) stats[t] = 0.f;
}

// features [B][128][N] -> x0b[b][n][0:128]
__global__ void transpose_x0_k(const float* __restrict__ feat, float* __restrict__ x0b) {
  __shared__ float tile[32][33];
  int b = blockIdx.z;
  int n0 = blockIdx.x * 32, c0 = blockIdx.y * 32;
  int tx = threadIdx.x;
  for (int ty = threadIdx.y; ty < 32; ty += 8)
    tile[ty][tx] = feat[((long)b * CH + c0 + ty) * NPTS + n0 + tx];
  __syncthreads();
  for (int ty = threadIdx.y; ty < 32; ty += 8)
    x0b[((long)b * NPTS + n0 + ty) * 128 + c0 + tx] = tile[tx][ty];
}

__global__ void prep_w_k(const float* __restrict__ W1, const float* __restrict__ W2,
                         float* __restrict__ Wm1, float* __restrict__ Wm2) {
  int t = blockIdx.x * 256 + threadIdx.x;
  if (t < 256 * 128) {
    int r = t >> 7, k = t & 127;
    Wm1[t] = (r < 128) ? (W1[r * 256 + k] - W1[r * 256 + 128 + k])
                       : W1[(r - 128) * 256 + 128 + k];
  }
  if (t < 512 * 128) {
    int r = t >> 7, k = t & 127;
    Wm2[t] = (r < 256) ? (W2[r * 256 + k] - W2[r * 256 + 128 + k])
                       : W2[(r - 256) * 256 + 128 + k];
  }
}

// sums (sum, sumsq) -> (scale, bias) per (b, col):  z = y*scale + bias
__global__ void finalize_scb_k(const float* __restrict__ stats, float2* __restrict__ scb,
                               int count, float cinv) {
  int t = blockIdx.x * 256 + threadIdx.x;
  if (t < count) {
    float mean = stats[t * 2] * cinv;
    float var = stats[t * 2 + 1] * cinv - mean * mean;
    float inv = rsqrtf(var + EPSI);
    scb[t] = make_float2(inv, -mean * inv);
  }
}

// ---------------- KNN ----------------
__global__ void knn_prep_k(const float* __restrict__ coords, float4* __restrict__ pts) {
  int b = blockIdx.y;
  int i = blockIdx.x * 256 + threadIdx.x;
  const float* cb = coords + (long)b * 3 * NPTS;
  float x = cb[i], y = cb[NPTS + i], z = cb[2 * NPTS + i];
  float sq = __fadd_rn(__fadd_rn(__fmul_rn(x, x), __fmul_rn(y, y)), __fmul_rn(z, z));
  pts[(long)b * NPTS + i] = make_float4(x, y, z, sq);
}

#define DIST(pi, pj, d2)                                                          \
  float dot = __fadd_rn(__fadd_rn(__fmul_rn((pi).x, (pj).x), __fmul_rn((pi).y, (pj).y)), \
                        __fmul_rn((pi).z, (pj).z));                               \
  float d2 = __fsub_rn(__fadd_rn((pi).w, (pj).w), __fmul_rn(2.0f, dot));

// Stable predicated insertion into ascending (d, id) list; ties keep earlier insert.
#define KNN_INSERT(d2v, jv)                                              \
  if ((d2v) < d[K17 - 1]) {                                              \
    _Pragma("unroll")                                                    \
    for (int s = K17 - 1; s > 0; --s) {                                  \
      if ((d2v) < d[s - 1]) { d[s] = d[s - 1]; id[s] = id[s - 1]; }      \
      else if ((d2v) < d[s]) { d[s] = (d2v); id[s] = (jv); }             \
    }                                                                    \
    if ((d2v) < d[0]) { d[0] = (d2v); id[0] = (jv); }                    \
  }

// Phase A: 32 sub-threads per point; sub s keeps top-2 of sample candidates
// j in [s*64, s*64+64) (sample = first 2048 points).
__global__ __launch_bounds__(256) void knn_phaseA_k(const float4* __restrict__ pts,
                                                    float2* __restrict__ pa) {
  int b = blockIdx.y;
  int ib = blockIdx.x & 127;
  int sg = blockIdx.x >> 7;          // 0..7
  int i = ib * 64 + (threadIdx.x & 63);
  int sub = sg * 4 + (threadIdx.x >> 6);   // 0..31
  const float4* P = pts + (long)b * NPTS;
  float4 pi = P[i];
  float d0 = BIGF, d1 = BIGF;
  int i0 = 0x7fffffff, i1 = 0x7fffffff;
  int j0 = sub * 64;
  for (int jj = 0; jj < 64; ++jj) {
    float4 pj = P[j0 + jj];
    DIST(pi, pj, d2)
    if (d2 < d1) {
      if (d2 < d0) { d1 = d0; i1 = i0; d0 = d2; i0 = j0 + jj; }
      else { d1 = d2; i1 = j0 + jj; }
    }
  }
  long base = (((long)b * NPTS + i) * 32 + sub) * 2;
  pa[base] = make_float2(d0, __int_as_float(i0));
  pa[base + 1] = make_float2(d1, __int_as_float(i1));
}

// Merge 32x2 partials -> tau = 17th smallest of the 64 sample distances
__global__ __launch_bounds__(256) void knn_mergeA_k(const float2* __restrict__ pa,
                                                    float* __restrict__ tau) {
  int b = blockIdx.y;
  int i = blockIdx.x * 256 + threadIdx.x;
  float d[K17]; int id[K17];
#pragma unroll
  for (int s = 0; s < K17; ++s) { d[s] = BIGF; id[s] = 0x7fffffff; }
  long base = ((long)b * NPTS + i) * 64;
  for (int c = 0; c < 64; ++c) {
    float2 v = pa[base + c];
    if (v.x < d[K17 - 1]) {
      int j = __float_as_int(v.y);
      KNN_INSERT(v.x, j);
    }
  }
  tau[(long)b * NPTS + i] = d[K17 - 1];
}

// Phase B: per (i, chunk) thread, append all candidates with d2 <= tau_i.
__global__ __launch_bounds__(256) void knn_filter_k(const float4* __restrict__ pts,
                                                    const float* __restrict__ tau,
                                                    float2* __restrict__ surv,
                                                    int* __restrict__ counts) {
  int b = blockIdx.z;
  int i = blockIdx.x * 256 + threadIdx.x;
  int chunk = blockIdx.y;
  const float4* P = pts + (long)b * NPTS;
  float4 pi = P[i];
  float t = tau[(long)b * NPTS + i];
  long sbase = (((long)b * NPTS + i) * NCH + chunk) * SCAP;
  int cnt = 0;
  int j0 = chunk * CHSZ;
#pragma unroll 2
  for (int jj = 0; jj < CHSZ; ++jj) {
    float4 pj = P[j0 + jj];
    DIST(pi, pj, d2)
    if (d2 <= t) {
      if (cnt < SCAP) surv[sbase + cnt] = make_float2(d2, __int_as_float(j0 + jj));
      cnt++;
    }
  }
  counts[((long)b * NPTS + i) * NCH + chunk] = cnt;
}

// Fused Merge-B: block = 32 points x 8 subs, each sub merges 4 chunks into a
// register top-17, 3-level LDS insert-merge tree.
__global__ __launch_bounds__(256) void knn_mergeB_k(const float2* __restrict__ surv,
                                                    const int* __restrict__ counts,
                                                    const float4* __restrict__ pts,
                                                    int* __restrict__ idxo) {
  __shared__ float2 lds[8][K17][32];
  int b = blockIdx.y;
  int pl = threadIdx.x & 31;
  int sub = threadIdx.x >> 5;
  int i = blockIdx.x * 32 + pl;
  const float4* P = pts + (long)b * NPTS;
  float4 pi = P[i];
  float d[K17]; int id[K17];
#pragma unroll
  for (int s = 0; s < K17; ++s) { d[s] = BIGF; id[s] = 0x7fffffff; }
  long cbase = ((long)b * NPTS + i) * NCH;
  int4 c4 = *(const int4*)(counts + cbase + sub * 4);
  int cnt4[4] = {c4.x, c4.y, c4.z, c4.w};
#pragma unroll
  for (int q = 0; q < 4; ++q) {
    int c = sub * 4 + q;
    int cnt = cnt4[q];
    if (cnt > SCAP) {
      int j0 = c * CHSZ;
      for (int jj = 0; jj < CHSZ; ++jj) {
        float4 pj = P[j0 + jj];
        DIST(pi, pj, d2)
        KNN_INSERT(d2, j0 + jj);
      }
    } else {
      long sb = (cbase + c) * SCAP;
      for (int p = 0; p < cnt; p += 2) {
        float4 v2 = *(const float4*)(surv + sb + p);
        if (v2.x < d[K17 - 1]) {
          int j = __float_as_int(v2.y);
          KNN_INSERT(v2.x, j);
        }
        if (p + 1 < cnt && v2.z < d[K17 - 1]) {
          int j = __float_as_int(v2.w);
          KNN_INSERT(v2.z, j);
        }
      }
    }
  }
#pragma unroll
  for (int s = 0; s < K17; ++s) lds[sub][s][pl] = make_float2(d[s], __int_as_float(id[s]));
  __syncthreads();
  if ((sub & 1) == 0) {
#pragma unroll
    for (int s = 0; s < K17; ++s) {
      float2 v = lds[sub + 1][s][pl];
      if (v.x < d[K17 - 1]) {
        int j = __float_as_int(v.y);
        KNN_INSERT(v.x, j);
      }
    }
  }
  __syncthreads();
  if ((sub & 1) == 0) {
#pragma unroll
    for (int s = 0; s < K17; ++s) lds[sub >> 1][s][pl] = make_float2(d[s], __int_as_float(id[s]));
  }
  __syncthreads();
  if (sub < 2) {
#pragma unroll
    for (int s = 0; s < K17; ++s) {
      float2 v = lds[2 * sub][s][pl];
      d[s] = v.x; id[s] = __float_as_int(v.y);
    }
#pragma unroll
    for (int s = 0; s < K17; ++s) {
      float2 v = lds[2 * sub + 1][s][pl];
      if (v.x < d[K17 - 1]) {
        int j = __float_as_int(v.y);
        KNN_INSERT(v.x, j);
      }
    }
  }
  __syncthreads();
  if (sub < 2) {
#pragma unroll
    for (int s = 0; s < K17; ++s) lds[sub][s][pl] = make_float2(d[s], __int_as_float(id[s]));
  }
  __syncthreads();
  if (sub == 0) {
#pragma unroll
    for (int s = 0; s < K17; ++s) {
      float2 v = lds[0][s][pl];
      d[s] = v.x; id[s] = __float_as_int(v.y);
    }
#pragma unroll
    for (int s = 0; s < K17; ++s) {
      float2 v = lds[1][s][pl];
      if (v.x < d[K17 - 1]) {
        int j = __float_as_int(v.y);
        KNN_INSERT(v.x, j);
      }
    }
    long ob = ((long)b * NPTS + i) * KNN;
#pragma unroll
    for (int s = 1; s < K17; ++s) idxo[ob + s - 1] = id[s];
  }
}

// ---------------- GEMM: Out[b][n][m] = sum_k X[b][n][k] * W[m][k] ----------------
#define GBN 128
#define GBM 64
#define GBK 32
__global__ __launch_bounds__(256) void gemm_xt_k(const float* __restrict__ X, int sx, long xbs,
                                                 const float* __restrict__ W, int K,
                                                 float* __restrict__ Out, int so, long obs) {
  __shared__ float Xs[GBK][GBN + 4];
  __shared__ float Ws[GBK][GBM + 4];
  int b = blockIdx.z;
  const float* Xb = X + (long)b * xbs;
  float* Ob = Out + (long)b * obs;
  int n0 = blockIdx.x * GBN, m0 = blockIdx.y * GBM;
  int tx = threadIdx.x, ty = threadIdx.y;
  int tid = ty * 16 + tx;
  float acc[8][4];
#pragma unroll
  for (int i = 0; i < 8; ++i)
#pragma unroll
    for (int j = 0; j < 4; ++j) acc[i][j] = 0.f;

  for (int k0 = 0; k0 < K; k0 += GBK) {
#pragma unroll
    for (int i = 0; i < 4; ++i) {
      int q = tid + i * 256;
      int r = q >> 3, kq = (q & 7) * 4;
      const float4 v = *(const float4*)(Xb + (long)(n0 + r) * sx + k0 + kq);
      Xs[kq][r] = v.x; Xs[kq + 1][r] = v.y; Xs[kq + 2][r] = v.z; Xs[kq + 3][r] = v.w;
    }
#pragma unroll
    for (int i = 0; i < 2; ++i) {
      int q = tid + i * 256;
      int r = q >> 3, kq = (q & 7) * 4;
      const float4 v = *(const float4*)(W + (long)(m0 + r) * K + k0 + kq);
      Ws[kq][r] = v.x; Ws[kq + 1][r] = v.y; Ws[kq + 2][r] = v.z; Ws[kq + 3][r] = v.w;
    }
    __syncthreads();
#pragma unroll
    for (int kk = 0; kk < GBK; ++kk) {
      float4 w4 = *(const float4*)&Ws[kk][tx * 4];
      float4 xa = *(const float4*)&Xs[kk][ty * 8];
      float4 xb4 = *(const float4*)&Xs[kk][ty * 8 + 4];
      float xs[8] = {xa.x, xa.y, xa.z, xa.w, xb4.x, xb4.y, xb4.z, xb4.w};
      float wv[4] = {w4.x, w4.y, w4.z, w4.w};
#pragma unroll
      for (int i = 0; i < 8; ++i)
#pragma unroll
        for (int j = 0; j < 4; ++j) acc[i][j] = fmaf(xs[i], wv[j], acc[i][j]);
    }
    __syncthreads();
  }
#pragma unroll
  for (int i = 0; i < 8; ++i) {
    float4 v = make_float4(acc[i][0], acc[i][1], acc[i][2], acc[i][3]);
    *(float4*)(Ob + (long)(n0 + ty * 8 + i) * so + m0 + tx * 4) = v;
  }
}

#define AFFLK4(v, a0, a1, a2, a3)                              \
  v.x = fmaf(v.x, a0.x, a0.y); v.x = fmaxf(v.x, SLOPE * v.x);  \
  v.y = fmaf(v.y, a1.x, a1.y); v.y = fmaxf(v.y, SLOPE * v.y);  \
  v.z = fmaf(v.z, a2.x, a2.y); v.z = fmaxf(v.z, SLOPE * v.z);  \
  v.w = fmaf(v.w, a3.x, a3.y); v.w = fmaxf(v.w, SLOPE * v.w);

// stage-3 GEMM: X = leaky(affine(ym1)) applied during staging. K=128, X stride 128.
__global__ __launch_bounds__(256) void gemm_aff_k(const float* __restrict__ X,
                                                  const float2* __restrict__ scb,
                                                  const float* __restrict__ W,
                                                  float* __restrict__ Out, int so, long obs) {
  __shared__ float Xs[GBK][GBN + 4];
  __shared__ float Ws[GBK][GBM + 4];
  int b = blockIdx.z;
  const float* Xb = X + (long)b * NPTS * 128;
  const float2* sc = scb + b * 128;
  float* Ob = Out + (long)b * obs;
  int n0 = blockIdx.x * GBN, m0 = blockIdx.y * GBM;
  int tx = threadIdx.x, ty = threadIdx.y;
  int tid = ty * 16 + tx;
  float acc[8][4];
#pragma unroll
  for (int i = 0; i < 8; ++i)
#pragma unroll
    for (int j = 0; j < 4; ++j) acc[i][j] = 0.f;

  for (int k0 = 0; k0 < 128; k0 += GBK) {
#pragma unroll
    for (int i = 0; i < 4; ++i) {
      int q = tid + i * 256;
      int r = q >> 3, kq = (q & 7) * 4;
      float4 v = *(const float4*)(Xb + (long)(n0 + r) * 128 + k0 + kq);
      float2 a0 = sc[k0 + kq], a1 = sc[k0 + kq + 1], a2 = sc[k0 + kq + 2], a3 = sc[k0 + kq + 3];
      AFFLK4(v, a0, a1, a2, a3)
      Xs[kq][r] = v.x; Xs[kq + 1][r] = v.y; Xs[kq + 2][r] = v.z; Xs[kq + 3][r] = v.w;
    }
#pragma unroll
    for (int i = 0; i < 2; ++i) {
      int q = tid + i * 256;
      int r = q >> 3, kq = (q & 7) * 4;
      const float4 v = *(const float4*)(W + (long)(m0 + r) * 128 + k0 + kq);
      Ws[kq][r] = v.x; Ws[kq + 1][r] = v.y; Ws[kq + 2][r] = v.z; Ws[kq + 3][r] = v.w;
    }
    __syncthreads();
#pragma unroll
    for (int kk = 0; kk < GBK; ++kk) {
      float4 w4 = *(const float4*)&Ws[kk][tx * 4];
      float4 xa = *(const float4*)&Xs[kk][ty * 8];
      float4 xb4 = *(const float4*)&Xs[kk][ty * 8 + 4];
      float xs[8] = {xa.x, xa.y, xa.z, xa.w, xb4.x, xb4.y, xb4.z, xb4.w};
      float wv[4] = {w4.x, w4.y, w4.z, w4.w};
#pragma unroll
      for (int i = 0; i < 8; ++i)
#pragma unroll
        for (int j = 0; j < 4; ++j) acc[i][j] = fmaf(xs[i], wv[j], acc[i][j]);
    }
    __syncthreads();
  }
#pragma unroll
  for (int i = 0; i < 8; ++i) {
    float4 v = make_float4(acc[i][0], acc[i][1], acc[i][2], acc[i][3]);
    *(float4*)(Ob + (long)(n0 + ty * 8 + i) * so + m0 + tx * 4) = v;
  }
}

// stage-4 GEMM: 128n x 64m tile + split-K 2-way (round-7 proven: 512 blocks =
// 2 blocks/CU so staging/barriers of one block overlap compute of the other).
// k-half 0 = x0b + ym1; k-half 1 = ym2 (segment-aligned split).
__global__ __launch_bounds__(256) void gemm_cat_k(const float* __restrict__ x0b,
                                                  const float* __restrict__ ym1,
                                                  const float* __restrict__ ym2,
                                                  const float2* __restrict__ scb1,
                                                  const float2* __restrict__ scb2,
                                                  const float* __restrict__ W,
                                                  float* __restrict__ OutA,
                                                  float* __restrict__ OutB) {
  __shared__ float Xs[GBK][GBN + 4];
  __shared__ float Ws[GBK][GBM + 4];
  int b = blockIdx.z;
  int mt = blockIdx.y & 1;
  int kh = blockIdx.y >> 1;
  float* Ob = (kh ? OutB : OutA) + (long)b * NPTS * 128;
  int n0 = blockIdx.x * GBN, m0 = mt * GBM;
  int tx = threadIdx.x, ty = threadIdx.y;
  int tid = ty * 16 + tx;
  float acc[8][4];
#pragma unroll
  for (int i = 0; i < 8; ++i)
#pragma unroll
    for (int j = 0; j < 4; ++j) acc[i][j] = 0.f;

  for (int ks = 0; ks < 8; ++ks) {
    int k0 = kh * 256 + ks * GBK;
    const float* Xb; long st_; const float2* sc_; int cb_;
    if (k0 < 128)      { Xb = x0b + (long)b * NPTS * 128; st_ = 128; sc_ = nullptr;        cb_ = 0; }
    else if (k0 < 256) { Xb = ym1 + (long)b * NPTS * 128; st_ = 128; sc_ = scb1 + b * 128; cb_ = 128; }
    else               { Xb = ym2 + (long)b * NPTS * 256; st_ = 256; sc_ = scb2 + b * 256; cb_ = 256; }
    int kl = k0 - cb_;
#pragma unroll
    for (int i = 0; i < 4; ++i) {
      int q = tid + i * 256;
      int r = q >> 3, kq = (q & 7) * 4;
      float4 v = *(const float4*)(Xb + (long)(n0 + r) * st_ + kl + kq);
      if (sc_) {
        float2 a0 = sc_[kl + kq], a1 = sc_[kl + kq + 1], a2 = sc_[kl + kq + 2], a3 = sc_[kl + kq + 3];
        AFFLK4(v, a0, a1, a2, a3)
      }
      Xs[kq][r] = v.x; Xs[kq + 1][r] = v.y; Xs[kq + 2][r] = v.z; Xs[kq + 3][r] = v.w;
    }
#pragma unroll
    for (int i = 0; i < 2; ++i) {
      int q = tid + i * 256;
      int r = q >> 3, kq = (q & 7) * 4;
      const float4 v = *(const float4*)(W + (long)(m0 + r) * 512 + k0 + kq);
      Ws[kq][r] = v.x; Ws[kq + 1][r] = v.y; Ws[kq + 2][r] = v.z; Ws[kq + 3][r] = v.w;
    }
    __syncthreads();
#pragma unroll
    for (int kk = 0; kk < GBK; ++kk) {
      float4 w4 = *(const float4*)&Ws[kk][tx * 4];
      float4 xa = *(const float4*)&Xs[kk][ty * 8];
      float4 xb4 = *(const float4*)&Xs[kk][ty * 8 + 4];
      float xs[8] = {xa.x, xa.y, xa.z, xa.w, xb4.x, xb4.y, xb4.z, xb4.w};
      float wv[4] = {w4.x, w4.y, w4.z, w4.w};
#pragma unroll
      for (int i = 0; i < 8; ++i)
#pragma unroll
        for (int j = 0; j < 4; ++j) acc[i][j] = fmaf(xs[i], wv[j], acc[i][j]);
    }
    __syncthreads();
  }
#pragma unroll
  for (int i = 0; i < 8; ++i) {
    float4 v = make_float4(acc[i][0], acc[i][1], acc[i][2], acc[i][3]);
    *(float4*)(Ob + (long)(n0 + ty * 8 + i) * 128 + m0 + tx * 4) = v;
  }
}

// ---------------- edge (EXACT round-0 proven config): y = u[n] + v[idx[n,k]] ----
// max over k + channel sum/sumsq. LOAD-BEARING, measured A/B — do not perturb:
// PPB=32, 1024 blocks, 4 blocks/CU x 4 waves = 16 waves/CU exact full residency;
// (b,ct) in blk bits 1-2 -> per-XCD gather table 2-4 MB L2-resident.
// Tried & failed: PPB=16 (114us), full-row CG=64 (126us), per-thread 16-gather
// batch (250us), nt hints (FETCH 44->30MB, time unchanged — latency equilibrium,
// not traffic-bound).
template <int CTILE, int PPB>
__global__ __launch_bounds__(256) void edge_max_t(const float* __restrict__ uv, int S, int voff,
                                                  int Cout, const int* __restrict__ idx,
                                                  float* __restrict__ ymax,
                                                  float* __restrict__ stats) {
  constexpr int CG = CTILE / 4;     // channel-groups (threads per point-row)
  constexpr int PSL = 256 / CG;     // point-slots per block
  __shared__ float ls[2][256][4];
  int blk = blockIdx.x;
  int c = (blk & 7) >> 1;           // combo 0..3
  int b = c >> 1;                   // batch
  int ct = c & 1;                   // channel tile
  int pblk = ((blk >> 3) << 1) | (blk & 1);
  int ch0 = ct * CTILE;
  const float* uvb = uv + (long)b * NPTS * S;
  const int* idxb = idx + (long)b * NPTS * KNN;
  float* ymb = ymax + (long)b * NPTS * Cout;
  int cg = threadIdx.x & (CG - 1);
  int ps = threadIdx.x / CG;
  int n0 = pblk * PPB;
  const float* vb = uvb + voff + ch0 + 4 * cg;
  float4 s = make_float4(0.f, 0.f, 0.f, 0.f);
  float4 s2 = make_float4(0.f, 0.f, 0.f, 0.f);
  for (int p = ps; p < PPB; p += PSL) {
    int n = n0 + p;
    const int* ip = idxb + n * KNN;
    int4 ia = *(const int4*)(ip);
    int4 ib4 = *(const int4*)(ip + 4);
    int4 ic = *(const int4*)(ip + 8);
    int4 id4 = *(const int4*)(ip + 12);
    int mi[KNN] = {ia.x, ia.y, ia.z, ia.w, ib4.x, ib4.y, ib4.z, ib4.w,
                   ic.x, ic.y, ic.z, ic.w, id4.x, id4.y, id4.z, id4.w};
    float4 u = *(const float4*)(uvb + (long)n * S + ch0 + 4 * cg);
    float4 mx = make_float4(-INFINITY, -INFINITY, -INFINITY, -INFINITY);
#pragma unroll
    for (int k = 0; k < KNN; ++k) {
      float4 v = *(const float4*)(vb + (long)mi[k] * S);
      float4 y;
      y.x = u.x + v.x; y.y = u.y + v.y; y.z = u.z + v.z; y.w = u.w + v.w;
      mx.x = fmaxf(mx.x, y.x); mx.y = fmaxf(mx.y, y.y);
      mx.z = fmaxf(mx.z, y.z); mx.w = fmaxf(mx.w, y.w);
      s.x += y.x; s.y += y.y; s.z += y.z; s.w += y.w;
      s2.x = fmaf(y.x, y.x, s2.x); s2.y = fmaf(y.y, y.y, s2.y);
      s2.z = fmaf(y.z, y.z, s2.z); s2.w = fmaf(y.w, y.w, s2.w);
    }
    *(float4*)(ymb + (long)n * Cout + ch0 + 4 * cg) = mx;
  }
  int t = threadIdx.x;
  ls[0][t][0] = s.x; ls[0][t][1] = s.y; ls[0][t][2] = s.z; ls[0][t][3] = s.w;
  ls[1][t][0] = s2.x; ls[1][t][1] = s2.y; ls[1][t][2] = s2.z; ls[1][t][3] = s2.w;
  __syncthreads();
  if (ps == 0) {
#pragma unroll
    for (int j = 1; j < PSL; ++j) {
      int q = j * CG + cg;
      s.x += ls[0][q][0]; s.y += ls[0][q][1]; s.z += ls[0][q][2]; s.w += ls[0][q][3];
      s2.x += ls[1][q][0]; s2.y += ls[1][q][1]; s2.z += ls[1][q][2]; s2.w += ls[1][q][3];
    }
    float* st = stats + ((long)b * Cout + ch0 + 4 * cg) * 2;
    atomicAdd(&st[0], s.x); atomicAdd(&st[1], s2.x);
    atomicAdd(&st[2], s.y); atomicAdd(&st[3], s2.y);
    atomicAdd(&st[4], s.z); atomicAdd(&st[5], s2.z);
    atomicAdd(&st[6], s.w); atomicAdd(&st[7], s2.w);
  }
}

// sum split-K halves -> y4; per-column (sum, sumsq) -> stats
__global__ void colstats2_k(float* __restrict__ y4, const float* __restrict__ y4b,
                            float* __restrict__ stats) {
  int b = blockIdx.y;
  int o = threadIdx.x & 127, slot = threadIdx.x >> 7;
  int n0 = blockIdx.x * 64;
  float s = 0.f, s2 = 0.f;
  for (int p = slot; p < 64; p += 2) {
    long off = ((long)b * NPTS + n0 + p) * 128 + o;
    float y = y4[off] + y4b[off];
    y4[off] = y;
    s += y;
    s2 = fmaf(y, y, s2);
  }
  float* st = stats + ((long)b * 128 + o) * 2;
  atomicAdd(&st[0], s);
  atomicAdd(&st[1], s2);
}

__global__ void final_k(const float* __restrict__ y3, const float* __restrict__ stats,
                        float* __restrict__ out) {
  __shared__ float tile[32][33];
  int b = blockIdx.z;
  int n0 = blockIdx.x * 32, o0 = blockIdx.y * 32;
  int tx = threadIdx.x;
  for (int ty = threadIdx.y; ty < 32; ty += 8) {
    int o = o0 + tx;
    const float* st = stats + ((long)b * 128 + o) * 2;
    float mean = st[0] * (1.f / 8192.f);
    float var = st[1] * (1.f / 8192.f) - mean * mean;
    float inv = rsqrtf(var + EPSI);
    float y = y3[((long)b * NPTS + n0 + ty) * 128 + o];
    float z = (y - mean) * inv;
    tile[ty][tx] = z >= 0.f ? z : SLOPE * z;
  }
  __syncthreads();
  for (int ty = threadIdx.y; ty < 32; ty += 8)
    out[((long)b * CH + o0 + ty) * NPTS + n0 + tx] = tile[tx][ty];
}

// ---------------- launch ----------------
extern "C" void kernel_launch(void* const* d_in, const int* in_sizes, int n_in,
                              void* d_out, int out_size, void* d_ws, size_t ws_size,
                              hipStream_t stream) {
  const float* coords = (const float*)d_in[0];
  const float* features = (const float*)d_in[1];
  const float* W1 = (const float*)d_in[2];
  const float* W2 = (const float*)d_in[3];
  const float* W3 = (const float*)d_in[4];
  float* out = (float*)d_out;
  char* ws = (char*)d_ws;

  int* idx = (int*)(ws + OFF_IDX);
  float* x0b = (float*)(ws + OFF_X0B);
  float* ym1 = (float*)(ws + OFF_YM1);
  float* ym2 = (float*)(ws + OFF_YM2);
  float* uv = (float*)(ws + OFF_UV);
  float* y4 = (float*)(ws + OFF_Y4);
  float2* surv = (float2*)(ws + OFF_SURV);
  float2* pa = (float2*)(ws + OFF_PA);
  int* counts = (int*)(ws + OFF_CNT);
  float* tau = (float*)(ws + OFF_TAU);
  float* wm1 = (float*)(ws + OFF_WM1);
  float* wm2 = (float*)(ws + OFF_WM2);
  float* stats = (float*)(ws + OFF_STATS);
  float2* scb1 = (float2*)(ws + OFF_SCB1);
  float2* scb2 = (float2*)(ws + OFF_SCB2);
  float4* pts4 = (float4*)(ws + OFF_PTS4);

  zero_stats_k<<<8, 256, 0, stream>>>(stats);
  // ---- KNN ----
  knn_prep_k<<<dim3(NPTS / 256, NB), 256, 0, stream>>>(coords, pts4);
  knn_phaseA_k<<<dim3(1024, NB), 256, 0, stream>>>(pts4, pa);
  knn_mergeA_k<<<dim3(NPTS / 256, NB), 256, 0, stream>>>(pa, tau);
  knn_filter_k<<<dim3(NPTS / 256, NCH, NB), 256, 0, stream>>>(pts4, tau, surv, counts);
  knn_mergeB_k<<<dim3(NPTS / 32, NB), 256, 0, stream>>>(surv, counts, pts4, idx);

  transpose_x0_k<<<dim3(NPTS / 32, CH / 32, NB), dim3(32, 8), 0, stream>>>(features, x0b);
  prep_w_k<<<256, 256, 0, stream>>>(W1, W2, wm1, wm2);

  // stage 2 (edge: 1024 blocks, PPB=32 — round-0 proven)
  gemm_xt_k<<<dim3(NPTS / GBN, 256 / GBM, NB), dim3(16, 16), 0, stream>>>(
      x0b, 128, (long)NPTS * 128, wm1, 128, uv, 256, (long)NPTS * 256);
  edge_max_t<64, 32><<<dim3(NPTS / 32 * 2 * NB), 256, 0, stream>>>(uv, 256, 128, 128, idx,
                                                                   ym1, stats);
  finalize_scb_k<<<1, 256, 0, stream>>>(stats, scb1, 256, 1.0f / 131072.0f);
  // stage 3
  gemm_aff_k<<<dim3(NPTS / GBN, 512 / GBM, NB), dim3(16, 16), 0, stream>>>(
      ym1, scb1, wm2, uv, 512, (long)NPTS * 512);
  edge_max_t<128, 32><<<dim3(NPTS / 32 * 2 * NB), 256, 0, stream>>>(uv, 512, 256, 256, idx,
                                                                    ym2, stats + 512);
  finalize_scb_k<<<2, 256, 0, stream>>>(stats + 512, scb2, 512, 1.0f / 131072.0f);
  // stage 4: 128x64 tile, split-K 2-way -> (64, 4, 2) = 512 blocks = 2/CU.
  // kh0 -> y4, kh1 -> uv (dead after stage-3 edge); colstats2 sums halves.
  gemm_cat_k<<<dim3(NPTS / GBN, 4, NB), dim3(16, 16), 0, stream>>>(
      x0b, ym1, ym2, scb1, scb2, W3, y4, uv);
  colstats2_k<<<dim3(NPTS / 64, NB), 256, 0, stream>>>(y4, uv, stats + 1536);
  final_k<<<dim3(NPTS / 32, CH / 32, NB), dim3(32, 8), 0, stream>>>(y4, stats + 1536, out);
}

// Round 11
// 486.981 us; speedup vs baseline: 1.2706x; 1.0037x over previous
//
#include <hip/hip_runtime.h>
#include <math.h>

#define NB 2
#define NPTS 8192
#define CH 128
#define KNN 16
#define K17 17
#define EPSI 1e-5f
#define SLOPE 0.2f
#define NCH 32        // filter chunks
#define CHSZ 256      // candidates per chunk
#define SCAP 16       // survivor cap per chunk. LOAD-BEARING at 16 (r9: SCAP=8
                      // overflow-rescan tail made fused mergeB 230us).
#define BIGF 3.0e38f

typedef float __attribute__((ext_vector_type(4))) f4v;

// ---------------- workspace layout (bytes) ----------------
// idx  [B][N][16] int            @ 0            (1 MB)
// x0b  [B][N][128] f32           @ 1,048,576    (8 MB)   } surv aliases
// ym1  [B][N][128] f32           @ 9,437,184    (8 MB)
// ym2  [B][N][256] f32           @ 17,825,792   (16 MB)
// uv   [B][N][512] f32           @ 34,603,008   (32 MB)  } stage-4: y4b partial (8MB)
// y4   [B][N][128] f32           @ 68,157,440   (8 MB)   } pa aliases y4
// counts [B][N][32] int          @ 76,546,048   (2 MB)
// tau                            @ 78,643,200   (64 KB)
// Wm1 [256][128]                 @ 78,708,736
// Wm2 [512][128]                 @ 78,839,808
// stats (2048 f32)               @ 79,101,952
// scb1 [B][128] float2           @ 79,110,144
// scb2 [B][256] float2           @ 79,112,192
// pts4 [B][N] float4             @ 79,116,288
#define OFF_IDX   0L
#define OFF_X0B   1048576L
#define OFF_YM1   9437184L
#define OFF_YM2   17825792L
#define OFF_UV    34603008L
#define OFF_Y4    68157440L
#define OFF_SURV  OFF_X0B
#define OFF_PA    OFF_Y4
#define OFF_CNT   76546048L
#define OFF_TAU   78643200L
#define OFF_WM1   78708736L
#define OFF_WM2   78839808L
#define OFF_STATS 79101952L
#define OFF_SCB1  79110144L
#define OFF_SCB2  79112192L
#define OFF_PTS4  79116288L

// SESSION LEDGER (measured A/B, do not retry):
//  - edge: 70us equilibrium survived: compiler-level gather batching (r1: batch
//    never materialized, VGPR stayed 40), full-row gathers (r3: L2 thrash),
//    PPB=16 (114us), nt hints (r8: FETCH 44->30MB, time UNCHANGED).
//    THIS ROUND: inline-asm forced 17-deep gather batch — discriminates
//    per-thread-MLP vs per-CU-miss-throughput. VGPR must jump >100 as proof.
//  - GEMMs: LDS-issue-bound; row-dot no-LDS (r6) WORSE; 128x64+split-K (r7) best.
//  - Grid-union fusion (r9): tail-latency pathology. Do not fuse.

// ---------------- small utility kernels ----------------

__global__ void zero_stats_k(float* __restrict__ stats) {
  int t = blockIdx.x * 256 + threadIdx.x;
  if (t < 2048) stats[t] = 0.f;
}

// features [B][128][N] -> x0b[b][n][0:128]
__global__ void transpose_x0_k(const float* __restrict__ feat, float* __restrict__ x0b) {
  __shared__ float tile[32][33];
  int b = blockIdx.z;
  int n0 = blockIdx.x * 32, c0 = blockIdx.y * 32;
  int tx = threadIdx.x;
  for (int ty = threadIdx.y; ty < 32; ty += 8)
    tile[ty][tx] = feat[((long)b * CH + c0 + ty) * NPTS + n0 + tx];
  __syncthreads();
  for (int ty = threadIdx.y; ty < 32; ty += 8)
    x0b[((long)b * NPTS + n0 + ty) * 128 + c0 + tx] = tile[tx][ty];
}

__global__ void prep_w_k(const float* __restrict__ W1, const float* __restrict__ W2,
                         float* __restrict__ Wm1, float* __restrict__ Wm2) {
  int t = blockIdx.x * 256 + threadIdx.x;
  if (t < 256 * 128) {
    int r = t >> 7, k = t & 127;
    Wm1[t] = (r < 128) ? (W1[r * 256 + k] - W1[r * 256 + 128 + k])
                       : W1[(r - 128) * 256 + 128 + k];
  }
  if (t < 512 * 128) {
    int r = t >> 7, k = t & 127;
    Wm2[t] = (r < 256) ? (W2[r * 256 + k] - W2[r * 256 + 128 + k])
                       : W2[(r - 256) * 256 + 128 + k];
  }
}

// sums (sum, sumsq) -> (scale, bias) per (b, col):  z = y*scale + bias
__global__ void finalize_scb_k(const float* __restrict__ stats, float2* __restrict__ scb,
                               int count, float cinv) {
  int t = blockIdx.x * 256 + threadIdx.x;
  if (t < count) {
    float mean = stats[t * 2] * cinv;
    float var = stats[t * 2 + 1] * cinv - mean * mean;
    float inv = rsqrtf(var + EPSI);
    scb[t] = make_float2(inv, -mean * inv);
  }
}

// ---------------- KNN ----------------
__global__ void knn_prep_k(const float* __restrict__ coords, float4* __restrict__ pts) {
  int b = blockIdx.y;
  int i = blockIdx.x * 256 + threadIdx.x;
  const float* cb = coords + (long)b * 3 * NPTS;
  float x = cb[i], y = cb[NPTS + i], z = cb[2 * NPTS + i];
  float sq = __fadd_rn(__fadd_rn(__fmul_rn(x, x), __fmul_rn(y, y)), __fmul_rn(z, z));
  pts[(long)b * NPTS + i] = make_float4(x, y, z, sq);
}

#define DIST(pi, pj, d2)                                                          \
  float dot = __fadd_rn(__fadd_rn(__fmul_rn((pi).x, (pj).x), __fmul_rn((pi).y, (pj).y)), \
                        __fmul_rn((pi).z, (pj).z));                               \
  float d2 = __fsub_rn(__fadd_rn((pi).w, (pj).w), __fmul_rn(2.0f, dot));

// Stable predicated insertion into ascending (d, id) list; ties keep earlier insert.
#define KNN_INSERT(d2v, jv)                                              \
  if ((d2v) < d[K17 - 1]) {                                              \
    _Pragma("unroll")                                                    \
    for (int s = K17 - 1; s > 0; --s) {                                  \
      if ((d2v) < d[s - 1]) { d[s] = d[s - 1]; id[s] = id[s - 1]; }      \
      else if ((d2v) < d[s]) { d[s] = (d2v); id[s] = (jv); }             \
    }                                                                    \
    if ((d2v) < d[0]) { d[0] = (d2v); id[0] = (jv); }                    \
  }

// Phase A: 32 sub-threads per point; sub s keeps top-2 of sample candidates
// j in [s*64, s*64+64) (sample = first 2048 points).
__global__ __launch_bounds__(256) void knn_phaseA_k(const float4* __restrict__ pts,
                                                    float2* __restrict__ pa) {
  int b = blockIdx.y;
  int ib = blockIdx.x & 127;
  int sg = blockIdx.x >> 7;          // 0..7
  int i = ib * 64 + (threadIdx.x & 63);
  int sub = sg * 4 + (threadIdx.x >> 6);   // 0..31
  const float4* P = pts + (long)b * NPTS;
  float4 pi = P[i];
  float d0 = BIGF, d1 = BIGF;
  int i0 = 0x7fffffff, i1 = 0x7fffffff;
  int j0 = sub * 64;
  for (int jj = 0; jj < 64; ++jj) {
    float4 pj = P[j0 + jj];
    DIST(pi, pj, d2)
    if (d2 < d1) {
      if (d2 < d0) { d1 = d0; i1 = i0; d0 = d2; i0 = j0 + jj; }
      else { d1 = d2; i1 = j0 + jj; }
    }
  }
  long base = (((long)b * NPTS + i) * 32 + sub) * 2;
  pa[base] = make_float2(d0, __int_as_float(i0));
  pa[base + 1] = make_float2(d1, __int_as_float(i1));
}

// Merge 32x2 partials -> tau = 17th smallest of the 64 sample distances
__global__ __launch_bounds__(256) void knn_mergeA_k(const float2* __restrict__ pa,
                                                    float* __restrict__ tau) {
  int b = blockIdx.y;
  int i = blockIdx.x * 256 + threadIdx.x;
  float d[K17]; int id[K17];
#pragma unroll
  for (int s = 0; s < K17; ++s) { d[s] = BIGF; id[s] = 0x7fffffff; }
  long base = ((long)b * NPTS + i) * 64;
  for (int c = 0; c < 64; ++c) {
    float2 v = pa[base + c];
    if (v.x < d[K17 - 1]) {
      int j = __float_as_int(v.y);
      KNN_INSERT(v.x, j);
    }
  }
  tau[(long)b * NPTS + i] = d[K17 - 1];
}

// Phase B: per (i, chunk) thread, append all candidates with d2 <= tau_i.
__global__ __launch_bounds__(256) void knn_filter_k(const float4* __restrict__ pts,
                                                    const float* __restrict__ tau,
                                                    float2* __restrict__ surv,
                                                    int* __restrict__ counts) {
  int b = blockIdx.z;
  int i = blockIdx.x * 256 + threadIdx.x;
  int chunk = blockIdx.y;
  const float4* P = pts + (long)b * NPTS;
  float4 pi = P[i];
  float t = tau[(long)b * NPTS + i];
  long sbase = (((long)b * NPTS + i) * NCH + chunk) * SCAP;
  int cnt = 0;
  int j0 = chunk * CHSZ;
#pragma unroll 2
  for (int jj = 0; jj < CHSZ; ++jj) {
    float4 pj = P[j0 + jj];
    DIST(pi, pj, d2)
    if (d2 <= t) {
      if (cnt < SCAP) surv[sbase + cnt] = make_float2(d2, __int_as_float(j0 + jj));
      cnt++;
    }
  }
  counts[((long)b * NPTS + i) * NCH + chunk] = cnt;
}

// Fused Merge-B: block = 32 points x 8 subs, each sub merges 4 chunks into a
// register top-17, 3-level LDS insert-merge tree.
__global__ __launch_bounds__(256) void knn_mergeB_k(const float2* __restrict__ surv,
                                                    const int* __restrict__ counts,
                                                    const float4* __restrict__ pts,
                                                    int* __restrict__ idxo) {
  __shared__ float2 lds[8][K17][32];
  int b = blockIdx.y;
  int pl = threadIdx.x & 31;
  int sub = threadIdx.x >> 5;
  int i = blockIdx.x * 32 + pl;
  const float4* P = pts + (long)b * NPTS;
  float4 pi = P[i];
  float d[K17]; int id[K17];
#pragma unroll
  for (int s = 0; s < K17; ++s) { d[s] = BIGF; id[s] = 0x7fffffff; }
  long cbase = ((long)b * NPTS + i) * NCH;
  int4 c4 = *(const int4*)(counts + cbase + sub * 4);
  int cnt4[4] = {c4.x, c4.y, c4.z, c4.w};
#pragma unroll
  for (int q = 0; q < 4; ++q) {
    int c = sub * 4 + q;
    int cnt = cnt4[q];
    if (cnt > SCAP) {
      int j0 = c * CHSZ;
      for (int jj = 0; jj < CHSZ; ++jj) {
        float4 pj = P[j0 + jj];
        DIST(pi, pj, d2)
        KNN_INSERT(d2, j0 + jj);
      }
    } else {
      long sb = (cbase + c) * SCAP;
      for (int p = 0; p < cnt; p += 2) {
        float4 v2 = *(const float4*)(surv + sb + p);
        if (v2.x < d[K17 - 1]) {
          int j = __float_as_int(v2.y);
          KNN_INSERT(v2.x, j);
        }
        if (p + 1 < cnt && v2.z < d[K17 - 1]) {
          int j = __float_as_int(v2.w);
          KNN_INSERT(v2.z, j);
        }
      }
    }
  }
#pragma unroll
  for (int s = 0; s < K17; ++s) lds[sub][s][pl] = make_float2(d[s], __int_as_float(id[s]));
  __syncthreads();
  if ((sub & 1) == 0) {
#pragma unroll
    for (int s = 0; s < K17; ++s) {
      float2 v = lds[sub + 1][s][pl];
      if (v.x < d[K17 - 1]) {
        int j = __float_as_int(v.y);
        KNN_INSERT(v.x, j);
      }
    }
  }
  __syncthreads();
  if ((sub & 1) == 0) {
#pragma unroll
    for (int s = 0; s < K17; ++s) lds[sub >> 1][s][pl] = make_float2(d[s], __int_as_float(id[s]));
  }
  __syncthreads();
  if (sub < 2) {
#pragma unroll
    for (int s = 0; s < K17; ++s) {
      float2 v = lds[2 * sub][s][pl];
      d[s] = v.x; id[s] = __float_as_int(v.y);
    }
#pragma unroll
    for (int s = 0; s < K17; ++s) {
      float2 v = lds[2 * sub + 1][s][pl];
      if (v.x < d[K17 - 1]) {
        int j = __float_as_int(v.y);
        KNN_INSERT(v.x, j);
      }
    }
  }
  __syncthreads();
  if (sub < 2) {
#pragma unroll
    for (int s = 0; s < K17; ++s) lds[sub][s][pl] = make_float2(d[s], __int_as_float(id[s]));
  }
  __syncthreads();
  if (sub == 0) {
#pragma unroll
    for (int s = 0; s < K17; ++s) {
      float2 v = lds[0][s][pl];
      d[s] = v.x; id[s] = __float_as_int(v.y);
    }
#pragma unroll
    for (int s = 0; s < K17; ++s) {
      float2 v = lds[1][s][pl];
      if (v.x < d[K17 - 1]) {
        int j = __float_as_int(v.y);
        KNN_INSERT(v.x, j);
      }
    }
    long ob = ((long)b * NPTS + i) * KNN;
#pragma unroll
    for (int s = 1; s < K17; ++s) idxo[ob + s - 1] = id[s];
  }
}

// ---------------- GEMM: Out[b][n][m] = sum_k X[b][n][k] * W[m][k] ----------------
#define GBN 128
#define GBM 64
#define GBK 32
__global__ __launch_bounds__(256) void gemm_xt_k(const float* __restrict__ X, int sx, long xbs,
                                                 const float* __restrict__ W, int K,
                                                 float* __restrict__ Out, int so, long obs) {
  __shared__ float Xs[GBK][GBN + 4];
  __shared__ float Ws[GBK][GBM + 4];
  int b = blockIdx.z;
  const float* Xb = X + (long)b * xbs;
  float* Ob = Out + (long)b * obs;
  int n0 = blockIdx.x * GBN, m0 = blockIdx.y * GBM;
  int tx = threadIdx.x, ty = threadIdx.y;
  int tid = ty * 16 + tx;
  float acc[8][4];
#pragma unroll
  for (int i = 0; i < 8; ++i)
#pragma unroll
    for (int j = 0; j < 4; ++j) acc[i][j] = 0.f;

  for (int k0 = 0; k0 < K; k0 += GBK) {
#pragma unroll
    for (int i = 0; i < 4; ++i) {
      int q = tid + i * 256;
      int r = q >> 3, kq = (q & 7) * 4;
      const float4 v = *(const float4*)(Xb + (long)(n0 + r) * sx + k0 + kq);
      Xs[kq][r] = v.x; Xs[kq + 1][r] = v.y; Xs[kq + 2][r] = v.z; Xs[kq + 3][r] = v.w;
    }
#pragma unroll
    for (int i = 0; i < 2; ++i) {
      int q = tid + i * 256;
      int r = q >> 3, kq = (q & 7) * 4;
      const float4 v = *(const float4*)(W + (long)(m0 + r) * K + k0 + kq);
      Ws[kq][r] = v.x; Ws[kq + 1][r] = v.y; Ws[kq + 2][r] = v.z; Ws[kq + 3][r] = v.w;
    }
    __syncthreads();
#pragma unroll
    for (int kk = 0; kk < GBK; ++kk) {
      float4 w4 = *(const float4*)&Ws[kk][tx * 4];
      float4 xa = *(const float4*)&Xs[kk][ty * 8];
      float4 xb4 = *(const float4*)&Xs[kk][ty * 8 + 4];
      float xs[8] = {xa.x, xa.y, xa.z, xa.w, xb4.x, xb4.y, xb4.z, xb4.w};
      float wv[4] = {w4.x, w4.y, w4.z, w4.w};
#pragma unroll
      for (int i = 0; i < 8; ++i)
#pragma unroll
        for (int j = 0; j < 4; ++j) acc[i][j] = fmaf(xs[i], wv[j], acc[i][j]);
    }
    __syncthreads();
  }
#pragma unroll
  for (int i = 0; i < 8; ++i) {
    float4 v = make_float4(acc[i][0], acc[i][1], acc[i][2], acc[i][3]);
    *(float4*)(Ob + (long)(n0 + ty * 8 + i) * so + m0 + tx * 4) = v;
  }
}

#define AFFLK4(v, a0, a1, a2, a3)                              \
  v.x = fmaf(v.x, a0.x, a0.y); v.x = fmaxf(v.x, SLOPE * v.x);  \
  v.y = fmaf(v.y, a1.x, a1.y); v.y = fmaxf(v.y, SLOPE * v.y);  \
  v.z = fmaf(v.z, a2.x, a2.y); v.z = fmaxf(v.z, SLOPE * v.z);  \
  v.w = fmaf(v.w, a3.x, a3.y); v.w = fmaxf(v.w, SLOPE * v.w);

// stage-3 GEMM: X = leaky(affine(ym1)) applied during staging. K=128, X stride 128.
__global__ __launch_bounds__(256) void gemm_aff_k(const float* __restrict__ X,
                                                  const float2* __restrict__ scb,
                                                  const float* __restrict__ W,
                                                  float* __restrict__ Out, int so, long obs) {
  __shared__ float Xs[GBK][GBN + 4];
  __shared__ float Ws[GBK][GBM + 4];
  int b = blockIdx.z;
  const float* Xb = X + (long)b * NPTS * 128;
  const float2* sc = scb + b * 128;
  float* Ob = Out + (long)b * obs;
  int n0 = blockIdx.x * GBN, m0 = blockIdx.y * GBM;
  int tx = threadIdx.x, ty = threadIdx.y;
  int tid = ty * 16 + tx;
  float acc[8][4];
#pragma unroll
  for (int i = 0; i < 8; ++i)
#pragma unroll
    for (int j = 0; j < 4; ++j) acc[i][j] = 0.f;

  for (int k0 = 0; k0 < 128; k0 += GBK) {
#pragma unroll
    for (int i = 0; i < 4; ++i) {
      int q = tid + i * 256;
      int r = q >> 3, kq = (q & 7) * 4;
      float4 v = *(const float4*)(Xb + (long)(n0 + r) * 128 + k0 + kq);
      float2 a0 = sc[k0 + kq], a1 = sc[k0 + kq + 1], a2 = sc[k0 + kq + 2], a3 = sc[k0 + kq + 3];
      AFFLK4(v, a0, a1, a2, a3)
      Xs[kq][r] = v.x; Xs[kq + 1][r] = v.y; Xs[kq + 2][r] = v.z; Xs[kq + 3][r] = v.w;
    }
#pragma unroll
    for (int i = 0; i < 2; ++i) {
      int q = tid + i * 256;
      int r = q >> 3, kq = (q & 7) * 4;
      const float4 v = *(const float4*)(W + (long)(m0 + r) * 128 + k0 + kq);
      Ws[kq][r] = v.x; Ws[kq + 1][r] = v.y; Ws[kq + 2][r] = v.z; Ws[kq + 3][r] = v.w;
    }
    __syncthreads();
#pragma unroll
    for (int kk = 0; kk < GBK; ++kk) {
      float4 w4 = *(const float4*)&Ws[kk][tx * 4];
      float4 xa = *(const float4*)&Xs[kk][ty * 8];
      float4 xb4 = *(const float4*)&Xs[kk][ty * 8 + 4];
      float xs[8] = {xa.x, xa.y, xa.z, xa.w, xb4.x, xb4.y, xb4.z, xb4.w};
      float wv[4] = {w4.x, w4.y, w4.z, w4.w};
#pragma unroll
      for (int i = 0; i < 8; ++i)
#pragma unroll
        for (int j = 0; j < 4; ++j) acc[i][j] = fmaf(xs[i], wv[j], acc[i][j]);
    }
    __syncthreads();
  }
#pragma unroll
  for (int i = 0; i < 8; ++i) {
    float4 v = make_float4(acc[i][0], acc[i][1], acc[i][2], acc[i][3]);
    *(float4*)(Ob + (long)(n0 + ty * 8 + i) * so + m0 + tx * 4) = v;
  }
}

// stage-4 GEMM: 128n x 64m tile + split-K 2-way (round-7 proven: 512 blocks =
// 2 blocks/CU so staging/barriers of one block overlap compute of the other).
// k-half 0 = x0b + ym1; k-half 1 = ym2 (segment-aligned split).
__global__ __launch_bounds__(256) void gemm_cat_k(const float* __restrict__ x0b,
                                                  const float* __restrict__ ym1,
                                                  const float* __restrict__ ym2,
                                                  const float2* __restrict__ scb1,
                                                  const float2* __restrict__ scb2,
                                                  const float* __restrict__ W,
                                                  float* __restrict__ OutA,
                                                  float* __restrict__ OutB) {
  __shared__ float Xs[GBK][GBN + 4];
  __shared__ float Ws[GBK][GBM + 4];
  int b = blockIdx.z;
  int mt = blockIdx.y & 1;
  int kh = blockIdx.y >> 1;
  float* Ob = (kh ? OutB : OutA) + (long)b * NPTS * 128;
  int n0 = blockIdx.x * GBN, m0 = mt * GBM;
  int tx = threadIdx.x, ty = threadIdx.y;
  int tid = ty * 16 + tx;
  float acc[8][4];
#pragma unroll
  for (int i = 0; i < 8; ++i)
#pragma unroll
    for (int j = 0; j < 4; ++j) acc[i][j] = 0.f;

  for (int ks = 0; ks < 8; ++ks) {
    int k0 = kh * 256 + ks * GBK;
    const float* Xb; long st_; const float2* sc_; int cb_;
    if (k0 < 128)      { Xb = x0b + (long)b * NPTS * 128; st_ = 128; sc_ = nullptr;        cb_ = 0; }
    else if (k0 < 256) { Xb = ym1 + (long)b * NPTS * 128; st_ = 128; sc_ = scb1 + b * 128; cb_ = 128; }
    else               { Xb = ym2 + (long)b * NPTS * 256; st_ = 256; sc_ = scb2 + b * 256; cb_ = 256; }
    int kl = k0 - cb_;
#pragma unroll
    for (int i = 0; i < 4; ++i) {
      int q = tid + i * 256;
      int r = q >> 3, kq = (q & 7) * 4;
      float4 v = *(const float4*)(Xb + (long)(n0 + r) * st_ + kl + kq);
      if (sc_) {
        float2 a0 = sc_[kl + kq], a1 = sc_[kl + kq + 1], a2 = sc_[kl + kq + 2], a3 = sc_[kl + kq + 3];
        AFFLK4(v, a0, a1, a2, a3)
      }
      Xs[kq][r] = v.x; Xs[kq + 1][r] = v.y; Xs[kq + 2][r] = v.z; Xs[kq + 3][r] = v.w;
    }
#pragma unroll
    for (int i = 0; i < 2; ++i) {
      int q = tid + i * 256;
      int r = q >> 3, kq = (q & 7) * 4;
      const float4 v = *(const float4*)(W + (long)(m0 + r) * 512 + k0 + kq);
      Ws[kq][r] = v.x; Ws[kq + 1][r] = v.y; Ws[kq + 2][r] = v.z; Ws[kq + 3][r] = v.w;
    }
    __syncthreads();
#pragma unroll
    for (int kk = 0; kk < GBK; ++kk) {
      float4 w4 = *(const float4*)&Ws[kk][tx * 4];
      float4 xa = *(const float4*)&Xs[kk][ty * 8];
      float4 xb4 = *(const float4*)&Xs[kk][ty * 8 + 4];
      float xs[8] = {xa.x, xa.y, xa.z, xa.w, xb4.x, xb4.y, xb4.z, xb4.w};
      float wv[4] = {w4.x, w4.y, w4.z, w4.w};
#pragma unroll
      for (int i = 0; i < 8; ++i)
#pragma unroll
        for (int j = 0; j < 4; ++j) acc[i][j] = fmaf(xs[i], wv[j], acc[i][j]);
    }
    __syncthreads();
  }
#pragma unroll
  for (int i = 0; i < 8; ++i) {
    float4 v = make_float4(acc[i][0], acc[i][1], acc[i][2], acc[i][3]);
    *(float4*)(Ob + (long)(n0 + ty * 8 + i) * 128 + m0 + tx * 4) = v;
  }
}

// ---------------- edge (round-0 grid + ROUND-11 forced gather batch) -----------
// y = u[n] + v[idx[n,k]]; max over k + channel sum/sumsq.
// Grid/layout LOAD-BEARING, byte-identical to the 487us build: PPB=32, 1024
// blocks, (b,ct) in blk bits 1-2 (per-XCD table 2-4MB), full residency.
// ROUND-11 experiment: the 16 gathers + u load are issued via inline-asm
// global_load_dwordx4 (compiler CANNOT sink them — r1's plain-HIP attempt was
// re-sunk, VGPR stayed 40), then ONE s_waitcnt vmcnt(0) + sched_barrier(0)
// (guide rule #18) before consumption => 17 outstanding misses per thread.
// Discriminates: per-thread-MLP-limited (time drops ~2x) vs per-CU miss
// throughput equilibrium (time unchanged => ROOFLINE). VGPR>100 = proof.
template <int CTILE, int PPB>
__global__ __launch_bounds__(256) void edge_max_t(const float* __restrict__ uv, int S, int voff,
                                                  int Cout, const int* __restrict__ idx,
                                                  float* __restrict__ ymax,
                                                  float* __restrict__ stats) {
  constexpr int CG = CTILE / 4;     // channel-groups (threads per point-row)
  constexpr int PSL = 256 / CG;     // point-slots per block
  __shared__ float ls[2][256][4];
  int blk = blockIdx.x;
  int c = (blk & 7) >> 1;           // combo 0..3
  int b = c >> 1;                   // batch
  int ct = c & 1;                   // channel tile
  int pblk = ((blk >> 3) << 1) | (blk & 1);
  int ch0 = ct * CTILE;
  const float* uvb = uv + (long)b * NPTS * S;
  const int* idxb = idx + (long)b * NPTS * KNN;
  float* ymb = ymax + (long)b * NPTS * Cout;
  int cg = threadIdx.x & (CG - 1);
  int ps = threadIdx.x / CG;
  int n0 = pblk * PPB;
  const float* vb = uvb + voff + ch0 + 4 * cg;
  float4 s = make_float4(0.f, 0.f, 0.f, 0.f);
  float4 s2 = make_float4(0.f, 0.f, 0.f, 0.f);
  for (int p = ps; p < PPB; p += PSL) {
    int n = n0 + p;
    const int* ip = idxb + n * KNN;
    int4 ia = *(const int4*)(ip);
    int4 ib4 = *(const int4*)(ip + 4);
    int4 ic = *(const int4*)(ip + 8);
    int4 id4 = *(const int4*)(ip + 12);
    int mi[KNN] = {ia.x, ia.y, ia.z, ia.w, ib4.x, ib4.y, ib4.z, ib4.w,
                   ic.x, ic.y, ic.z, ic.w, id4.x, id4.y, id4.z, id4.w};
    // ---- forced 17-deep load batch: u + 16 gathers all in flight ----
    f4v u, v[KNN];
    {
      const float* up = uvb + (long)n * S + ch0 + 4 * cg;
      asm volatile("global_load_dwordx4 %0, %1, off" : "=v"(u) : "v"(up));
    }
#pragma unroll
    for (int k = 0; k < KNN; ++k) {
      const float* ap = vb + (long)mi[k] * S;
      asm volatile("global_load_dwordx4 %0, %1, off" : "=v"(v[k]) : "v"(ap));
    }
    asm volatile("s_waitcnt vmcnt(0)" ::: "memory");
    __builtin_amdgcn_sched_barrier(0);
    // ---- consume ----
    float4 mx = make_float4(-INFINITY, -INFINITY, -INFINITY, -INFINITY);
#pragma unroll
    for (int k = 0; k < KNN; ++k) {
      float yx = u[0] + v[k][0];
      float yy = u[1] + v[k][1];
      float yz = u[2] + v[k][2];
      float yw = u[3] + v[k][3];
      mx.x = fmaxf(mx.x, yx); mx.y = fmaxf(mx.y, yy);
      mx.z = fmaxf(mx.z, yz); mx.w = fmaxf(mx.w, yw);
      s.x += yx; s.y += yy; s.z += yz; s.w += yw;
      s2.x = fmaf(yx, yx, s2.x); s2.y = fmaf(yy, yy, s2.y);
      s2.z = fmaf(yz, yz, s2.z); s2.w = fmaf(yw, yw, s2.w);
    }
    *(float4*)(ymb + (long)n * Cout + ch0 + 4 * cg) = mx;
  }
  int t = threadIdx.x;
  ls[0][t][0] = s.x; ls[0][t][1] = s.y; ls[0][t][2] = s.z; ls[0][t][3] = s.w;
  ls[1][t][0] = s2.x; ls[1][t][1] = s2.y; ls[1][t][2] = s2.z; ls[1][t][3] = s2.w;
  __syncthreads();
  if (ps == 0) {
#pragma unroll
    for (int j = 1; j < PSL; ++j) {
      int q = j * CG + cg;
      s.x += ls[0][q][0]; s.y += ls[0][q][1]; s.z += ls[0][q][2]; s.w += ls[0][q][3];
      s2.x += ls[1][q][0]; s2.y += ls[1][q][1]; s2.z += ls[1][q][2]; s2.w += ls[1][q][3];
    }
    float* st = stats + ((long)b * Cout + ch0 + 4 * cg) * 2;
    atomicAdd(&st[0], s.x); atomicAdd(&st[1], s2.x);
    atomicAdd(&st[2], s.y); atomicAdd(&st[3], s2.y);
    atomicAdd(&st[4], s.z); atomicAdd(&st[5], s2.z);
    atomicAdd(&st[6], s.w); atomicAdd(&st[7], s2.w);
  }
}

// sum split-K halves -> y4; per-column (sum, sumsq) -> stats
__global__ void colstats2_k(float* __restrict__ y4, const float* __restrict__ y4b,
                            float* __restrict__ stats) {
  int b = blockIdx.y;
  int o = threadIdx.x & 127, slot = threadIdx.x >> 7;
  int n0 = blockIdx.x * 64;
  float s = 0.f, s2 = 0.f;
  for (int p = slot; p < 64; p += 2) {
    long off = ((long)b * NPTS + n0 + p) * 128 + o;
    float y = y4[off] + y4b[off];
    y4[off] = y;
    s += y;
    s2 = fmaf(y, y, s2);
  }
  float* st = stats + ((long)b * 128 + o) * 2;
  atomicAdd(&st[0], s);
  atomicAdd(&st[1], s2);
}

__global__ void final_k(const float* __restrict__ y3, const float* __restrict__ stats,
                        float* __restrict__ out) {
  __shared__ float tile[32][33];
  int b = blockIdx.z;
  int n0 = blockIdx.x * 32, o0 = blockIdx.y * 32;
  int tx = threadIdx.x;
  for (int ty = threadIdx.y; ty < 32; ty += 8) {
    int o = o0 + tx;
    const float* st = stats + ((long)b * 128 + o) * 2;
    float mean = st[0] * (1.f / 8192.f);
    float var = st[1] * (1.f / 8192.f) - mean * mean;
    float inv = rsqrtf(var + EPSI);
    float y = y3[((long)b * NPTS + n0 + ty) * 128 + o];
    float z = (y - mean) * inv;
    tile[ty][tx] = z >= 0.f ? z : SLOPE * z;
  }
  __syncthreads();
  for (int ty = threadIdx.y; ty < 32; ty += 8)
    out[((long)b * CH + o0 + ty) * NPTS + n0 + tx] = tile[tx][ty];
}

// ---------------- launch ----------------
extern "C" void kernel_launch(void* const* d_in, const int* in_sizes, int n_in,
                              void* d_out, int out_size, void* d_ws, size_t ws_size,
                              hipStream_t stream) {
  const float* coords = (const float*)d_in[0];
  const float* features = (const float*)d_in[1];
  const float* W1 = (const float*)d_in[2];
  const float* W2 = (const float*)d_in[3];
  const float* W3 = (const float*)d_in[4];
  float* out = (float*)d_out;
  char* ws = (char*)d_ws;

  int* idx = (int*)(ws + OFF_IDX);
  float* x0b = (float*)(ws + OFF_X0B);
  float* ym1 = (float*)(ws + OFF_YM1);
  float* ym2 = (float*)(ws + OFF_YM2);
  float* uv = (float*)(ws + OFF_UV);
  float* y4 = (float*)(ws + OFF_Y4);
  float2* surv = (float2*)(ws + OFF_SURV);
  float2* pa = (float2*)(ws + OFF_PA);
  int* counts = (int*)(ws + OFF_CNT);
  float* tau = (float*)(ws + OFF_TAU);
  float* wm1 = (float*)(ws + OFF_WM1);
  float* wm2 = (float*)(ws + OFF_WM2);
  float* stats = (float*)(ws + OFF_STATS);
  float2* scb1 = (float2*)(ws + OFF_SCB1);
  float2* scb2 = (float2*)(ws + OFF_SCB2);
  float4* pts4 = (float4*)(ws + OFF_PTS4);

  zero_stats_k<<<8, 256, 0, stream>>>(stats);
  // ---- KNN ----
  knn_prep_k<<<dim3(NPTS / 256, NB), 256, 0, stream>>>(coords, pts4);
  knn_phaseA_k<<<dim3(1024, NB), 256, 0, stream>>>(pts4, pa);
  knn_mergeA_k<<<dim3(NPTS / 256, NB), 256, 0, stream>>>(pa, tau);
  knn_filter_k<<<dim3(NPTS / 256, NCH, NB), 256, 0, stream>>>(pts4, tau, surv, counts);
  knn_mergeB_k<<<dim3(NPTS / 32, NB), 256, 0, stream>>>(surv, counts, pts4, idx);

  transpose_x0_k<<<dim3(NPTS / 32, CH / 32, NB), dim3(32, 8), 0, stream>>>(features, x0b);
  prep_w_k<<<256, 256, 0, stream>>>(W1, W2, wm1, wm2);

  // stage 2 (edge: 1024 blocks, PPB=32 — round-0 proven grid)
  gemm_xt_k<<<dim3(NPTS / GBN, 256 / GBM, NB), dim3(16, 16), 0, stream>>>(
      x0b, 128, (long)NPTS * 128, wm1, 128, uv, 256, (long)NPTS * 256);
  edge_max_t<64, 32><<<dim3(NPTS / 32 * 2 * NB), 256, 0, stream>>>(uv, 256, 128, 128, idx,
                                                                   ym1, stats);
  finalize_scb_k<<<1, 256, 0, stream>>>(stats, scb1, 256, 1.0f / 131072.0f);
  // stage 3
  gemm_aff_k<<<dim3(NPTS / GBN, 512 / GBM, NB), dim3(16, 16), 0, stream>>>(
      ym1, scb1, wm2, uv, 512, (long)NPTS * 512);
  edge_max_t<128, 32><<<dim3(NPTS / 32 * 2 * NB), 256, 0, stream>>>(uv, 512, 256, 256, idx,
                                                                    ym2, stats + 512);
  finalize_scb_k<<<2, 256, 0, stream>>>(stats + 512, scb2, 512, 1.0f / 131072.0f);
  // stage 4: 128x64 tile, split-K 2-way -> (64, 4, 2) = 512 blocks = 2/CU.
  gemm_cat_k<<<dim3(NPTS / GBN, 4, NB), dim3(16, 16), 0, stream>>>(
      x0b, ym1, ym2, scb1, scb2, W3, y4, uv);
  colstats2_k<<<dim3(NPTS / 64, NB), 256, 0, stream>>>(y4, uv, stats + 1536);
  final_k<<<dim3(NPTS / 32, CH / 32, NB), dim3(32, 8), 0, stream>>>(y4, stats + 1536, out);
}

// Round 12
// 486.839 us; speedup vs baseline: 1.2709x; 1.0003x over previous
//
#include <hip/hip_runtime.h>
#include <math.h>

#define NB 2
#define NPTS 8192
#define CH 128
#define KNN 16
#define K17 17
#define EPSI 1e-5f
#define SLOPE 0.2f
#define NCH 32        // filter chunks
#define CHSZ 256      // candidates per chunk
#define SCAP 16       // survivor cap per chunk. LOAD-BEARING at 16 (r9: SCAP=8
                      // overflow-rescan tail made fused mergeB 230us).
#define BIGF 3.0e38f

// ---------------- workspace layout (bytes) ----------------
#define OFF_IDX   0L
#define OFF_X0B   1048576L
#define OFF_YM1   9437184L
#define OFF_YM2   17825792L
#define OFF_UV    34603008L
#define OFF_Y4    68157440L
#define OFF_SURV  OFF_X0B
#define OFF_PA    OFF_Y4
#define OFF_CNT   76546048L
#define OFF_TAU   78643200L
#define OFF_WM1   78708736L
#define OFF_WM2   78839808L
#define OFF_STATS 79101952L
#define OFF_SCB1  79110144L
#define OFF_SCB2  79112192L
#define OFF_PTS4  79116288L

// SESSION LEDGER (measured A/B, do not retry):
//  - edge 70us equilibrium. Attempts: r1 plain-HIP 16-batch (re-sunk, VGPR 40),
//    r3 full-row gathers (L2 thrash), r3 PPB=16 (114us), r8 nt hints (FETCH
//    44->30MB, time UNCHANGED), r11 inline-asm 17-batch (regalloc SPILLED it:
//    VGPR 48 not 110, FETCH +1.3MB spill traffic, time unchanged -> inconclusive).
//    r12 (this): VGPR-FREE depth via global_load_lds per-lane-gather DMA.
//    Discriminator: Model A (wave-MLP-limited) -> ~2x faster; Model B (per-CU
//    miss-service cap) -> unchanged -> ROOFLINE.
//  - GEMMs: LDS-issue-bound; row-dot no-LDS (r6) WORSE; 128x64+split-K (r7) best.
//  - Grid-union fusion (r9): tail-latency pathology. Do not fuse.

// per-lane gathered 16B global -> (wave-uniform base + lane*16) LDS, async DMA.
__device__ __forceinline__ void gload_lds16(const float* g, float4* l) {
  __builtin_amdgcn_global_load_lds(
      (__attribute__((address_space(1))) void*)(void*)g,
      (__attribute__((address_space(3))) void*)(void*)l, 16, 0, 0);
}

// ---------------- small utility kernels ----------------

__global__ void zero_stats_k(float* __restrict__ stats) {
  int t = blockIdx.x * 256 + threadIdx.x;
  if (t < 2048) stats[t] = 0.f;
}

// features [B][128][N] -> x0b[b][n][0:128]
__global__ void transpose_x0_k(const float* __restrict__ feat, float* __restrict__ x0b) {
  __shared__ float tile[32][33];
  int b = blockIdx.z;
  int n0 = blockIdx.x * 32, c0 = blockIdx.y * 32;
  int tx = threadIdx.x;
  for (int ty = threadIdx.y; ty < 32; ty += 8)
    tile[ty][tx] = feat[((long)b * CH + c0 + ty) * NPTS + n0 + tx];
  __syncthreads();
  for (int ty = threadIdx.y; ty < 32; ty += 8)
    x0b[((long)b * NPTS + n0 + ty) * 128 + c0 + tx] = tile[tx][ty];
}

__global__ void prep_w_k(const float* __restrict__ W1, const float* __restrict__ W2,
                         float* __restrict__ Wm1, float* __restrict__ Wm2) {
  int t = blockIdx.x * 256 + threadIdx.x;
  if (t < 256 * 128) {
    int r = t >> 7, k = t & 127;
    Wm1[t] = (r < 128) ? (W1[r * 256 + k] - W1[r * 256 + 128 + k])
                       : W1[(r - 128) * 256 + 128 + k];
  }
  if (t < 512 * 128) {
    int r = t >> 7, k = t & 127;
    Wm2[t] = (r < 256) ? (W2[r * 256 + k] - W2[r * 256 + 128 + k])
                       : W2[(r - 256) * 256 + 128 + k];
  }
}

// sums (sum, sumsq) -> (scale, bias) per (b, col):  z = y*scale + bias
__global__ void finalize_scb_k(const float* __restrict__ stats, float2* __restrict__ scb,
                               int count, float cinv) {
  int t = blockIdx.x * 256 + threadIdx.x;
  if (t < count) {
    float mean = stats[t * 2] * cinv;
    float var = stats[t * 2 + 1] * cinv - mean * mean;
    float inv = rsqrtf(var + EPSI);
    scb[t] = make_float2(inv, -mean * inv);
  }
}

// ---------------- KNN ----------------
__global__ void knn_prep_k(const float* __restrict__ coords, float4* __restrict__ pts) {
  int b = blockIdx.y;
  int i = blockIdx.x * 256 + threadIdx.x;
  const float* cb = coords + (long)b * 3 * NPTS;
  float x = cb[i], y = cb[NPTS + i], z = cb[2 * NPTS + i];
  float sq = __fadd_rn(__fadd_rn(__fmul_rn(x, x), __fmul_rn(y, y)), __fmul_rn(z, z));
  pts[(long)b * NPTS + i] = make_float4(x, y, z, sq);
}

#define DIST(pi, pj, d2)                                                          \
  float dot = __fadd_rn(__fadd_rn(__fmul_rn((pi).x, (pj).x), __fmul_rn((pi).y, (pj).y)), \
                        __fmul_rn((pi).z, (pj).z));                               \
  float d2 = __fsub_rn(__fadd_rn((pi).w, (pj).w), __fmul_rn(2.0f, dot));

// Stable predicated insertion into ascending (d, id) list; ties keep earlier insert.
#define KNN_INSERT(d2v, jv)                                              \
  if ((d2v) < d[K17 - 1]) {                                              \
    _Pragma("unroll")                                                    \
    for (int s = K17 - 1; s > 0; --s) {                                  \
      if ((d2v) < d[s - 1]) { d[s] = d[s - 1]; id[s] = id[s - 1]; }      \
      else if ((d2v) < d[s]) { d[s] = (d2v); id[s] = (jv); }             \
    }                                                                    \
    if ((d2v) < d[0]) { d[0] = (d2v); id[0] = (jv); }                    \
  }

// Phase A: 32 sub-threads per point; sub s keeps top-2 of sample candidates
// j in [s*64, s*64+64) (sample = first 2048 points).
__global__ __launch_bounds__(256) void knn_phaseA_k(const float4* __restrict__ pts,
                                                    float2* __restrict__ pa) {
  int b = blockIdx.y;
  int ib = blockIdx.x & 127;
  int sg = blockIdx.x >> 7;          // 0..7
  int i = ib * 64 + (threadIdx.x & 63);
  int sub = sg * 4 + (threadIdx.x >> 6);   // 0..31
  const float4* P = pts + (long)b * NPTS;
  float4 pi = P[i];
  float d0 = BIGF, d1 = BIGF;
  int i0 = 0x7fffffff, i1 = 0x7fffffff;
  int j0 = sub * 64;
  for (int jj = 0; jj < 64; ++jj) {
    float4 pj = P[j0 + jj];
    DIST(pi, pj, d2)
    if (d2 < d1) {
      if (d2 < d0) { d1 = d0; i1 = i0; d0 = d2; i0 = j0 + jj; }
      else { d1 = d2; i1 = j0 + jj; }
    }
  }
  long base = (((long)b * NPTS + i) * 32 + sub) * 2;
  pa[base] = make_float2(d0, __int_as_float(i0));
  pa[base + 1] = make_float2(d1, __int_as_float(i1));
}

// Merge 32x2 partials -> tau = 17th smallest of the 64 sample distances
__global__ __launch_bounds__(256) void knn_mergeA_k(const float2* __restrict__ pa,
                                                    float* __restrict__ tau) {
  int b = blockIdx.y;
  int i = blockIdx.x * 256 + threadIdx.x;
  float d[K17]; int id[K17];
#pragma unroll
  for (int s = 0; s < K17; ++s) { d[s] = BIGF; id[s] = 0x7fffffff; }
  long base = ((long)b * NPTS + i) * 64;
  for (int c = 0; c < 64; ++c) {
    float2 v = pa[base + c];
    if (v.x < d[K17 - 1]) {
      int j = __float_as_int(v.y);
      KNN_INSERT(v.x, j);
    }
  }
  tau[(long)b * NPTS + i] = d[K17 - 1];
}

// Phase B: per (i, chunk) thread, append all candidates with d2 <= tau_i.
__global__ __launch_bounds__(256) void knn_filter_k(const float4* __restrict__ pts,
                                                    const float* __restrict__ tau,
                                                    float2* __restrict__ surv,
                                                    int* __restrict__ counts) {
  int b = blockIdx.z;
  int i = blockIdx.x * 256 + threadIdx.x;
  int chunk = blockIdx.y;
  const float4* P = pts + (long)b * NPTS;
  float4 pi = P[i];
  float t = tau[(long)b * NPTS + i];
  long sbase = (((long)b * NPTS + i) * NCH + chunk) * SCAP;
  int cnt = 0;
  int j0 = chunk * CHSZ;
#pragma unroll 2
  for (int jj = 0; jj < CHSZ; ++jj) {
    float4 pj = P[j0 + jj];
    DIST(pi, pj, d2)
    if (d2 <= t) {
      if (cnt < SCAP) surv[sbase + cnt] = make_float2(d2, __int_as_float(j0 + jj));
      cnt++;
    }
  }
  counts[((long)b * NPTS + i) * NCH + chunk] = cnt;
}

// Fused Merge-B: block = 32 points x 8 subs, each sub merges 4 chunks into a
// register top-17, 3-level LDS insert-merge tree.
__global__ __launch_bounds__(256) void knn_mergeB_k(const float2* __restrict__ surv,
                                                    const int* __restrict__ counts,
                                                    const float4* __restrict__ pts,
                                                    int* __restrict__ idxo) {
  __shared__ float2 lds[8][K17][32];
  int b = blockIdx.y;
  int pl = threadIdx.x & 31;
  int sub = threadIdx.x >> 5;
  int i = blockIdx.x * 32 + pl;
  const float4* P = pts + (long)b * NPTS;
  float4 pi = P[i];
  float d[K17]; int id[K17];
#pragma unroll
  for (int s = 0; s < K17; ++s) { d[s] = BIGF; id[s] = 0x7fffffff; }
  long cbase = ((long)b * NPTS + i) * NCH;
  int4 c4 = *(const int4*)(counts + cbase + sub * 4);
  int cnt4[4] = {c4.x, c4.y, c4.z, c4.w};
#pragma unroll
  for (int q = 0; q < 4; ++q) {
    int c = sub * 4 + q;
    int cnt = cnt4[q];
    if (cnt > SCAP) {
      int j0 = c * CHSZ;
      for (int jj = 0; jj < CHSZ; ++jj) {
        float4 pj = P[j0 + jj];
        DIST(pi, pj, d2)
        KNN_INSERT(d2, j0 + jj);
      }
    } else {
      long sb = (cbase + c) * SCAP;
      for (int p = 0; p < cnt; p += 2) {
        float4 v2 = *(const float4*)(surv + sb + p);
        if (v2.x < d[K17 - 1]) {
          int j = __float_as_int(v2.y);
          KNN_INSERT(v2.x, j);
        }
        if (p + 1 < cnt && v2.z < d[K17 - 1]) {
          int j = __float_as_int(v2.w);
          KNN_INSERT(v2.z, j);
        }
      }
    }
  }
#pragma unroll
  for (int s = 0; s < K17; ++s) lds[sub][s][pl] = make_float2(d[s], __int_as_float(id[s]));
  __syncthreads();
  if ((sub & 1) == 0) {
#pragma unroll
    for (int s = 0; s < K17; ++s) {
      float2 v = lds[sub + 1][s][pl];
      if (v.x < d[K17 - 1]) {
        int j = __float_as_int(v.y);
        KNN_INSERT(v.x, j);
      }
    }
  }
  __syncthreads();
  if ((sub & 1) == 0) {
#pragma unroll
    for (int s = 0; s < K17; ++s) lds[sub >> 1][s][pl] = make_float2(d[s], __int_as_float(id[s]));
  }
  __syncthreads();
  if (sub < 2) {
#pragma unroll
    for (int s = 0; s < K17; ++s) {
      float2 v = lds[2 * sub][s][pl];
      d[s] = v.x; id[s] = __float_as_int(v.y);
    }
#pragma unroll
    for (int s = 0; s < K17; ++s) {
      float2 v = lds[2 * sub + 1][s][pl];
      if (v.x < d[K17 - 1]) {
        int j = __float_as_int(v.y);
        KNN_INSERT(v.x, j);
      }
    }
  }
  __syncthreads();
  if (sub < 2) {
#pragma unroll
    for (int s = 0; s < K17; ++s) lds[sub][s][pl] = make_float2(d[s], __int_as_float(id[s]));
  }
  __syncthreads();
  if (sub == 0) {
#pragma unroll
    for (int s = 0; s < K17; ++s) {
      float2 v = lds[0][s][pl];
      d[s] = v.x; id[s] = __float_as_int(v.y);
    }
#pragma unroll
    for (int s = 0; s < K17; ++s) {
      float2 v = lds[1][s][pl];
      if (v.x < d[K17 - 1]) {
        int j = __float_as_int(v.y);
        KNN_INSERT(v.x, j);
      }
    }
    long ob = ((long)b * NPTS + i) * KNN;
#pragma unroll
    for (int s = 1; s < K17; ++s) idxo[ob + s - 1] = id[s];
  }
}

// ---------------- GEMM: Out[b][n][m] = sum_k X[b][n][k] * W[m][k] ----------------
#define GBN 128
#define GBM 64
#define GBK 32
__global__ __launch_bounds__(256) void gemm_xt_k(const float* __restrict__ X, int sx, long xbs,
                                                 const float* __restrict__ W, int K,
                                                 float* __restrict__ Out, int so, long obs) {
  __shared__ float Xs[GBK][GBN + 4];
  __shared__ float Ws[GBK][GBM + 4];
  int b = blockIdx.z;
  const float* Xb = X + (long)b * xbs;
  float* Ob = Out + (long)b * obs;
  int n0 = blockIdx.x * GBN, m0 = blockIdx.y * GBM;
  int tx = threadIdx.x, ty = threadIdx.y;
  int tid = ty * 16 + tx;
  float acc[8][4];
#pragma unroll
  for (int i = 0; i < 8; ++i)
#pragma unroll
    for (int j = 0; j < 4; ++j) acc[i][j] = 0.f;

  for (int k0 = 0; k0 < K; k0 += GBK) {
#pragma unroll
    for (int i = 0; i < 4; ++i) {
      int q = tid + i * 256;
      int r = q >> 3, kq = (q & 7) * 4;
      const float4 v = *(const float4*)(Xb + (long)(n0 + r) * sx + k0 + kq);
      Xs[kq][r] = v.x; Xs[kq + 1][r] = v.y; Xs[kq + 2][r] = v.z; Xs[kq + 3][r] = v.w;
    }
#pragma unroll
    for (int i = 0; i < 2; ++i) {
      int q = tid + i * 256;
      int r = q >> 3, kq = (q & 7) * 4;
      const float4 v = *(const float4*)(W + (long)(m0 + r) * K + k0 + kq);
      Ws[kq][r] = v.x; Ws[kq + 1][r] = v.y; Ws[kq + 2][r] = v.z; Ws[kq + 3][r] = v.w;
    }
    __syncthreads();
#pragma unroll
    for (int kk = 0; kk < GBK; ++kk) {
      float4 w4 = *(const float4*)&Ws[kk][tx * 4];
      float4 xa = *(const float4*)&Xs[kk][ty * 8];
      float4 xb4 = *(const float4*)&Xs[kk][ty * 8 + 4];
      float xs[8] = {xa.x, xa.y, xa.z, xa.w, xb4.x, xb4.y, xb4.z, xb4.w};
      float wv[4] = {w4.x, w4.y, w4.z, w4.w};
#pragma unroll
      for (int i = 0; i < 8; ++i)
#pragma unroll
        for (int j = 0; j < 4; ++j) acc[i][j] = fmaf(xs[i], wv[j], acc[i][j]);
    }
    __syncthreads();
  }
#pragma unroll
  for (int i = 0; i < 8; ++i) {
    float4 v = make_float4(acc[i][0], acc[i][1], acc[i][2], acc[i][3]);
    *(float4*)(Ob + (long)(n0 + ty * 8 + i) * so + m0 + tx * 4) = v;
  }
}

#define AFFLK4(v, a0, a1, a2, a3)                              \
  v.x = fmaf(v.x, a0.x, a0.y); v.x = fmaxf(v.x, SLOPE * v.x);  \
  v.y = fmaf(v.y, a1.x, a1.y); v.y = fmaxf(v.y, SLOPE * v.y);  \
  v.z = fmaf(v.z, a2.x, a2.y); v.z = fmaxf(v.z, SLOPE * v.z);  \
  v.w = fmaf(v.w, a3.x, a3.y); v.w = fmaxf(v.w, SLOPE * v.w);

// stage-3 GEMM: X = leaky(affine(ym1)) applied during staging. K=128, X stride 128.
__global__ __launch_bounds__(256) void gemm_aff_k(const float* __restrict__ X,
                                                  const float2* __restrict__ scb,
                                                  const float* __restrict__ W,
                                                  float* __restrict__ Out, int so, long obs) {
  __shared__ float Xs[GBK][GBN + 4];
  __shared__ float Ws[GBK][GBM + 4];
  int b = blockIdx.z;
  const float* Xb = X + (long)b * NPTS * 128;
  const float2* sc = scb + b * 128;
  float* Ob = Out + (long)b * obs;
  int n0 = blockIdx.x * GBN, m0 = blockIdx.y * GBM;
  int tx = threadIdx.x, ty = threadIdx.y;
  int tid = ty * 16 + tx;
  float acc[8][4];
#pragma unroll
  for (int i = 0; i < 8; ++i)
#pragma unroll
    for (int j = 0; j < 4; ++j) acc[i][j] = 0.f;

  for (int k0 = 0; k0 < 128; k0 += GBK) {
#pragma unroll
    for (int i = 0; i < 4; ++i) {
      int q = tid + i * 256;
      int r = q >> 3, kq = (q & 7) * 4;
      float4 v = *(const float4*)(Xb + (long)(n0 + r) * 128 + k0 + kq);
      float2 a0 = sc[k0 + kq], a1 = sc[k0 + kq + 1], a2 = sc[k0 + kq + 2], a3 = sc[k0 + kq + 3];
      AFFLK4(v, a0, a1, a2, a3)
      Xs[kq][r] = v.x; Xs[kq + 1][r] = v.y; Xs[kq + 2][r] = v.z; Xs[kq + 3][r] = v.w;
    }
#pragma unroll
    for (int i = 0; i < 2; ++i) {
      int q = tid + i * 256;
      int r = q >> 3, kq = (q & 7) * 4;
      const float4 v = *(const float4*)(W + (long)(m0 + r) * 128 + k0 + kq);
      Ws[kq][r] = v.x; Ws[kq + 1][r] = v.y; Ws[kq + 2][r] = v.z; Ws[kq + 3][r] = v.w;
    }
    __syncthreads();
#pragma unroll
    for (int kk = 0; kk < GBK; ++kk) {
      float4 w4 = *(const float4*)&Ws[kk][tx * 4];
      float4 xa = *(const float4*)&Xs[kk][ty * 8];
      float4 xb4 = *(const float4*)&Xs[kk][ty * 8 + 4];
      float xs[8] = {xa.x, xa.y, xa.z, xa.w, xb4.x, xb4.y, xb4.z, xb4.w};
      float wv[4] = {w4.x, w4.y, w4.z, w4.w};
#pragma unroll
      for (int i = 0; i < 8; ++i)
#pragma unroll
        for (int j = 0; j < 4; ++j) acc[i][j] = fmaf(xs[i], wv[j], acc[i][j]);
    }
    __syncthreads();
  }
#pragma unroll
  for (int i = 0; i < 8; ++i) {
    float4 v = make_float4(acc[i][0], acc[i][1], acc[i][2], acc[i][3]);
    *(float4*)(Ob + (long)(n0 + ty * 8 + i) * so + m0 + tx * 4) = v;
  }
}

// stage-4 GEMM: 128n x 64m tile + split-K 2-way (round-7 proven: 512 blocks =
// 2 blocks/CU so staging/barriers of one block overlap compute of the other).
// k-half 0 = x0b + ym1; k-half 1 = ym2 (segment-aligned split).
__global__ __launch_bounds__(256) void gemm_cat_k(const float* __restrict__ x0b,
                                                  const float* __restrict__ ym1,
                                                  const float* __restrict__ ym2,
                                                  const float2* __restrict__ scb1,
                                                  const float2* __restrict__ scb2,
                                                  const float* __restrict__ W,
                                                  float* __restrict__ OutA,
                                                  float* __restrict__ OutB) {
  __shared__ float Xs[GBK][GBN + 4];
  __shared__ float Ws[GBK][GBM + 4];
  int b = blockIdx.z;
  int mt = blockIdx.y & 1;
  int kh = blockIdx.y >> 1;
  float* Ob = (kh ? OutB : OutA) + (long)b * NPTS * 128;
  int n0 = blockIdx.x * GBN, m0 = mt * GBM;
  int tx = threadIdx.x, ty = threadIdx.y;
  int tid = ty * 16 + tx;
  float acc[8][4];
#pragma unroll
  for (int i = 0; i < 8; ++i)
#pragma unroll
    for (int j = 0; j < 4; ++j) acc[i][j] = 0.f;

  for (int ks = 0; ks < 8; ++ks) {
    int k0 = kh * 256 + ks * GBK;
    const float* Xb; long st_; const float2* sc_; int cb_;
    if (k0 < 128)      { Xb = x0b + (long)b * NPTS * 128; st_ = 128; sc_ = nullptr;        cb_ = 0; }
    else if (k0 < 256) { Xb = ym1 + (long)b * NPTS * 128; st_ = 128; sc_ = scb1 + b * 128; cb_ = 128; }
    else               { Xb = ym2 + (long)b * NPTS * 256; st_ = 256; sc_ = scb2 + b * 256; cb_ = 256; }
    int kl = k0 - cb_;
#pragma unroll
    for (int i = 0; i < 4; ++i) {
      int q = tid + i * 256;
      int r = q >> 3, kq = (q & 7) * 4;
      float4 v = *(const float4*)(Xb + (long)(n0 + r) * st_ + kl + kq);
      if (sc_) {
        float2 a0 = sc_[kl + kq], a1 = sc_[kl + kq + 1], a2 = sc_[kl + kq + 2], a3 = sc_[kl + kq + 3];
        AFFLK4(v, a0, a1, a2, a3)
      }
      Xs[kq][r] = v.x; Xs[kq + 1][r] = v.y; Xs[kq + 2][r] = v.z; Xs[kq + 3][r] = v.w;
    }
#pragma unroll
    for (int i = 0; i < 2; ++i) {
      int q = tid + i * 256;
      int r = q >> 3, kq = (q & 7) * 4;
      const float4 v = *(const float4*)(W + (long)(m0 + r) * 512 + k0 + kq);
      Ws[kq][r] = v.x; Ws[kq + 1][r] = v.y; Ws[kq + 2][r] = v.z; Ws[kq + 3][r] = v.w;
    }
    __syncthreads();
#pragma unroll
    for (int kk = 0; kk < GBK; ++kk) {
      float4 w4 = *(const float4*)&Ws[kk][tx * 4];
      float4 xa = *(const float4*)&Xs[kk][ty * 8];
      float4 xb4 = *(const float4*)&Xs[kk][ty * 8 + 4];
      float xs[8] = {xa.x, xa.y, xa.z, xa.w, xb4.x, xb4.y, xb4.z, xb4.w};
      float wv[4] = {w4.x, w4.y, w4.z, w4.w};
#pragma unroll
      for (int i = 0; i < 8; ++i)
#pragma unroll
        for (int j = 0; j < 4; ++j) acc[i][j] = fmaf(xs[i], wv[j], acc[i][j]);
    }
    __syncthreads();
  }
#pragma unroll
  for (int i = 0; i < 8; ++i) {
    float4 v = make_float4(acc[i][0], acc[i][1], acc[i][2], acc[i][3]);
    *(float4*)(Ob + (long)(n0 + ty * 8 + i) * 128 + m0 + tx * 4) = v;
  }
}

// ---------------- edge (round-0 grid + ROUND-12 LDS-DMA gather pipeline) ------
// y = u[n] + v[idx[n,k]]; max over k + channel sum/sumsq.
// Grid/layout LOAD-BEARING (PPB=32, 1024 blocks, (b,ct) in blk bits 1-2).
// ROUND-12: gathers issued via global_load_lds with PER-LANE global addresses
// (m173) -> zero VGPR destination cost, so regalloc CANNOT serialize the batch
// (the r1/r11 failure mode). 8 DMAs in flight per wave (8 x 1KB LDS slots),
// vmcnt(0), consume via ds_read_b128, lgkmcnt(0) drain (slot-reuse hazard),
// repeat for k=8..15. Accumulation order k=0..15 unchanged -> bit-identical.
// LDS 32KB/block x 4 blocks/CU = 128KB; stats scratch aliases the slots after
// a draining __syncthreads. Discriminator: Model A -> ~2x; Model B -> ROOFLINE.
template <int CTILE, int PPB>
__global__ __launch_bounds__(256) void edge_max_t(const float* __restrict__ uv, int S, int voff,
                                                  int Cout, const int* __restrict__ idx,
                                                  float* __restrict__ ymax,
                                                  float* __restrict__ stats) {
  constexpr int CG = CTILE / 4;     // channel-groups (threads per point-row)
  constexpr int PSL = 256 / CG;     // point-slots per block
  __shared__ float4 kb[4 * 8 * 64]; // 32KB: [wave][kslot 0..7][lane] float4
  int blk = blockIdx.x;
  int c = (blk & 7) >> 1;           // combo 0..3
  int b = c >> 1;                   // batch
  int ct = c & 1;                   // channel tile
  int pblk = ((blk >> 3) << 1) | (blk & 1);
  int ch0 = ct * CTILE;
  const float* uvb = uv + (long)b * NPTS * S;
  const int* idxb = idx + (long)b * NPTS * KNN;
  float* ymb = ymax + (long)b * NPTS * Cout;
  int cg = threadIdx.x & (CG - 1);
  int ps = threadIdx.x / CG;
  int n0 = pblk * PPB;
  int wid = threadIdx.x >> 6;
  int lane = threadIdx.x & 63;
  float4* kwb = kb + wid * 8 * 64;  // this wave's 8 x 64-lane slots
  const float* vb = uvb + voff + ch0 + 4 * cg;
  float4 s = make_float4(0.f, 0.f, 0.f, 0.f);
  float4 s2 = make_float4(0.f, 0.f, 0.f, 0.f);
  for (int p = ps; p < PPB; p += PSL) {
    int n = n0 + p;
    const int* ip = idxb + n * KNN;
    int4 ia = *(const int4*)(ip);
    int4 ib4 = *(const int4*)(ip + 4);
    int4 ic = *(const int4*)(ip + 8);
    int4 id4 = *(const int4*)(ip + 12);
    int mi[KNN] = {ia.x, ia.y, ia.z, ia.w, ib4.x, ib4.y, ib4.z, ib4.w,
                   ic.x, ic.y, ic.z, ic.w, id4.x, id4.y, id4.z, id4.w};
    float4 u = *(const float4*)(uvb + (long)n * S + ch0 + 4 * cg);
    float4 mx = make_float4(-INFINITY, -INFINITY, -INFINITY, -INFINITY);
    // ---- group 0: 8 async LDS-DMA gathers in flight ----
#pragma unroll
    for (int k = 0; k < 8; ++k)
      gload_lds16(vb + (long)mi[k] * S, kwb + k * 64);
    asm volatile("s_waitcnt vmcnt(0)" ::: "memory");
    __builtin_amdgcn_sched_barrier(0);
#pragma unroll
    for (int k = 0; k < 8; ++k) {
      float4 v = kwb[k * 64 + lane];
      float yx = u.x + v.x, yy = u.y + v.y, yz = u.z + v.z, yw = u.w + v.w;
      mx.x = fmaxf(mx.x, yx); mx.y = fmaxf(mx.y, yy);
      mx.z = fmaxf(mx.z, yz); mx.w = fmaxf(mx.w, yw);
      s.x += yx; s.y += yy; s.z += yz; s.w += yw;
      s2.x = fmaf(yx, yx, s2.x); s2.y = fmaf(yy, yy, s2.y);
      s2.z = fmaf(yz, yz, s2.z); s2.w = fmaf(yw, yw, s2.w);
    }
    // drain ds_reads before the slots are overwritten by group-1 DMA
    asm volatile("s_waitcnt lgkmcnt(0)" ::: "memory");
    __builtin_amdgcn_sched_barrier(0);
    // ---- group 1: k=8..15 ----
#pragma unroll
    for (int k = 8; k < 16; ++k)
      gload_lds16(vb + (long)mi[k] * S, kwb + (k - 8) * 64);
    asm volatile("s_waitcnt vmcnt(0)" ::: "memory");
    __builtin_amdgcn_sched_barrier(0);
#pragma unroll
    for (int k = 0; k < 8; ++k) {
      float4 v = kwb[k * 64 + lane];
      float yx = u.x + v.x, yy = u.y + v.y, yz = u.z + v.z, yw = u.w + v.w;
      mx.x = fmaxf(mx.x, yx); mx.y = fmaxf(mx.y, yy);
      mx.z = fmaxf(mx.z, yz); mx.w = fmaxf(mx.w, yw);
      s.x += yx; s.y += yy; s.z += yz; s.w += yw;
      s2.x = fmaf(yx, yx, s2.x); s2.y = fmaf(yy, yy, s2.y);
      s2.z = fmaf(yz, yz, s2.z); s2.w = fmaf(yw, yw, s2.w);
    }
    *(float4*)(ymb + (long)n * Cout + ch0 + 4 * cg) = mx;
    // drain before next iteration's group-0 DMA reuses the slots
    asm volatile("s_waitcnt lgkmcnt(0)" ::: "memory");
    __builtin_amdgcn_sched_barrier(0);
  }
  // all waves' DMAs drained by the barrier -> safe to alias kb as stats scratch
  __syncthreads();
  float* ls0 = (float*)kb;          // [256][4]
  float* ls1 = ls0 + 1024;          // [256][4]
  int t = threadIdx.x;
  ls0[t * 4 + 0] = s.x; ls0[t * 4 + 1] = s.y; ls0[t * 4 + 2] = s.z; ls0[t * 4 + 3] = s.w;
  ls1[t * 4 + 0] = s2.x; ls1[t * 4 + 1] = s2.y; ls1[t * 4 + 2] = s2.z; ls1[t * 4 + 3] = s2.w;
  __syncthreads();
  if (ps == 0) {
#pragma unroll
    for (int j = 1; j < PSL; ++j) {
      int q = j * CG + cg;
      s.x += ls0[q * 4 + 0]; s.y += ls0[q * 4 + 1]; s.z += ls0[q * 4 + 2]; s.w += ls0[q * 4 + 3];
      s2.x += ls1[q * 4 + 0]; s2.y += ls1[q * 4 + 1]; s2.z += ls1[q * 4 + 2]; s2.w += ls1[q * 4 + 3];
    }
    float* st = stats + ((long)b * Cout + ch0 + 4 * cg) * 2;
    atomicAdd(&st[0], s.x); atomicAdd(&st[1], s2.x);
    atomicAdd(&st[2], s.y); atomicAdd(&st[3], s2.y);
    atomicAdd(&st[4], s.z); atomicAdd(&st[5], s2.z);
    atomicAdd(&st[6], s.w); atomicAdd(&st[7], s2.w);
  }
}

// sum split-K halves -> y4; per-column (sum, sumsq) -> stats
__global__ void colstats2_k(float* __restrict__ y4, const float* __restrict__ y4b,
                            float* __restrict__ stats) {
  int b = blockIdx.y;
  int o = threadIdx.x & 127, slot = threadIdx.x >> 7;
  int n0 = blockIdx.x * 64;
  float s = 0.f, s2 = 0.f;
  for (int p = slot; p < 64; p += 2) {
    long off = ((long)b * NPTS + n0 + p) * 128 + o;
    float y = y4[off] + y4b[off];
    y4[off] = y;
    s += y;
    s2 = fmaf(y, y, s2);
  }
  float* st = stats + ((long)b * 128 + o) * 2;
  atomicAdd(&st[0], s);
  atomicAdd(&st[1], s2);
}

__global__ void final_k(const float* __restrict__ y3, const float* __restrict__ stats,
                        float* __restrict__ out) {
  __shared__ float tile[32][33];
  int b = blockIdx.z;
  int n0 = blockIdx.x * 32, o0 = blockIdx.y * 32;
  int tx = threadIdx.x;
  for (int ty = threadIdx.y; ty < 32; ty += 8) {
    int o = o0 + tx;
    const float* st = stats + ((long)b * 128 + o) * 2;
    float mean = st[0] * (1.f / 8192.f);
    float var = st[1] * (1.f / 8192.f) - mean * mean;
    float inv = rsqrtf(var + EPSI);
    float y = y3[((long)b * NPTS + n0 + ty) * 128 + o];
    float z = (y - mean) * inv;
    tile[ty][tx] = z >= 0.f ? z : SLOPE * z;
  }
  __syncthreads();
  for (int ty = threadIdx.y; ty < 32; ty += 8)
    out[((long)b * CH + o0 + ty) * NPTS + n0 + tx] = tile[tx][ty];
}

// ---------------- launch ----------------
extern "C" void kernel_launch(void* const* d_in, const int* in_sizes, int n_in,
                              void* d_out, int out_size, void* d_ws, size_t ws_size,
                              hipStream_t stream) {
  const float* coords = (const float*)d_in[0];
  const float* features = (const float*)d_in[1];
  const float* W1 = (const float*)d_in[2];
  const float* W2 = (const float*)d_in[3];
  const float* W3 = (const float*)d_in[4];
  float* out = (float*)d_out;
  char* ws = (char*)d_ws;

  int* idx = (int*)(ws + OFF_IDX);
  float* x0b = (float*)(ws + OFF_X0B);
  float* ym1 = (float*)(ws + OFF_YM1);
  float* ym2 = (float*)(ws + OFF_YM2);
  float* uv = (float*)(ws + OFF_UV);
  float* y4 = (float*)(ws + OFF_Y4);
  float2* surv = (float2*)(ws + OFF_SURV);
  float2* pa = (float2*)(ws + OFF_PA);
  int* counts = (int*)(ws + OFF_CNT);
  float* tau = (float*)(ws + OFF_TAU);
  float* wm1 = (float*)(ws + OFF_WM1);
  float* wm2 = (float*)(ws + OFF_WM2);
  float* stats = (float*)(ws + OFF_STATS);
  float2* scb1 = (float2*)(ws + OFF_SCB1);
  float2* scb2 = (float2*)(ws + OFF_SCB2);
  float4* pts4 = (float4*)(ws + OFF_PTS4);

  zero_stats_k<<<8, 256, 0, stream>>>(stats);
  // ---- KNN ----
  knn_prep_k<<<dim3(NPTS / 256, NB), 256, 0, stream>>>(coords, pts4);
  knn_phaseA_k<<<dim3(1024, NB), 256, 0, stream>>>(pts4, pa);
  knn_mergeA_k<<<dim3(NPTS / 256, NB), 256, 0, stream>>>(pa, tau);
  knn_filter_k<<<dim3(NPTS / 256, NCH, NB), 256, 0, stream>>>(pts4, tau, surv, counts);
  knn_mergeB_k<<<dim3(NPTS / 32, NB), 256, 0, stream>>>(surv, counts, pts4, idx);

  transpose_x0_k<<<dim3(NPTS / 32, CH / 32, NB), dim3(32, 8), 0, stream>>>(features, x0b);
  prep_w_k<<<256, 256, 0, stream>>>(W1, W2, wm1, wm2);

  // stage 2 (edge: 1024 blocks, PPB=32 — round-0 proven grid)
  gemm_xt_k<<<dim3(NPTS / GBN, 256 / GBM, NB), dim3(16, 16), 0, stream>>>(
      x0b, 128, (long)NPTS * 128, wm1, 128, uv, 256, (long)NPTS * 256);
  edge_max_t<64, 32><<<dim3(NPTS / 32 * 2 * NB), 256, 0, stream>>>(uv, 256, 128, 128, idx,
                                                                   ym1, stats);
  finalize_scb_k<<<1, 256, 0, stream>>>(stats, scb1, 256, 1.0f / 131072.0f);
  // stage 3
  gemm_aff_k<<<dim3(NPTS / GBN, 512 / GBM, NB), dim3(16, 16), 0, stream>>>(
      ym1, scb1, wm2, uv, 512, (long)NPTS * 512);
  edge_max_t<128, 32><<<dim3(NPTS / 32 * 2 * NB), 256, 0, stream>>>(uv, 512, 256, 256, idx,
                                                                    ym2, stats + 512);
  finalize_scb_k<<<2, 256, 0, stream>>>(stats + 512, scb2, 512, 1.0f / 131072.0f);
  // stage 4: 128x64 tile, split-K 2-way -> (64, 4, 2) = 512 blocks = 2/CU.
  gemm_cat_k<<<dim3(NPTS / GBN, 4, NB), dim3(16, 16), 0, stream>>>(
      x0b, ym1, ym2, scb1, scb2, W3, y4, uv);
  colstats2_k<<<dim3(NPTS / 64, NB), 256, 0, stream>>>(y4, uv, stats + 1536);
  final_k<<<dim3(NPTS / 32, CH / 32, NB), dim3(32, 8), 0, stream>>>(y4, stats + 1536, out);
}

// Round 13
// 483.045 us; speedup vs baseline: 1.2809x; 1.0079x over previous
//
#include <hip/hip_runtime.h>
#include <math.h>

#define NB 2
#define NPTS 8192
#define CH 128
#define KNN 16
#define K17 17
#define EPSI 1e-5f
#define SLOPE 0.2f
#define NCH 32        // filter chunks
#define CHSZ 256      // candidates per chunk
#define SCAP 16       // survivor cap per chunk. LOAD-BEARING at 16 (r9: SCAP=8
                      // overflow-rescan tail made fused mergeB 230us).
#define BIGF 3.0e38f

// ---------------- workspace layout (bytes) ----------------
#define OFF_IDX   0L
#define OFF_X0B   1048576L
#define OFF_YM1   9437184L
#define OFF_YM2   17825792L
#define OFF_UV    34603008L
#define OFF_Y4    68157440L
#define OFF_SURV  OFF_X0B
#define OFF_PA    OFF_Y4
#define OFF_CNT   76546048L
#define OFF_TAU   78643200L
#define OFF_WM1   78708736L
#define OFF_WM2   78839808L
#define OFF_STATS 79101952L
#define OFF_SCB1  79110144L
#define OFF_SCB2  79112192L
#define OFF_PTS4  79116288L

// SESSION LEDGER (measured A/B, do not retry):
//  - edge equilibrium: r1 plain-HIP batch (re-sunk), r3 full-row (L2 thrash),
//    r3 PPB=16 (114us), r8 nt hints (FETCH -32%, time unchanged), r11 asm batch
//    (regalloc spilled, VGPR 48). r12 LDS-DMA 8-deep MATERIALIZED (LDS 32768,
//    VGPR 44): 70 -> 65.4us (+7%). => mostly per-CU miss-service cap (Model B),
//    small elastic component. r13 (this): counted-vmcnt smoothing (T4) — last
//    depth lever; null => ROOFLINE.
//  - GEMMs: LDS-issue-bound; row-dot no-LDS (r6) WORSE; 128x64+split-K (r7) best.
//  - Grid-union fusion (r9): tail-latency pathology. Do not fuse.
//  - knn_mergeB now visible at ~65us (VALUBusy 32%, insert-chain bound).

// per-lane gathered 16B global -> (wave-uniform base + lane*16) LDS, async DMA.
__device__ __forceinline__ void gload_lds16(const float* g, float4* l) {
  __builtin_amdgcn_global_load_lds(
      (__attribute__((address_space(1))) void*)(void*)g,
      (__attribute__((address_space(3))) void*)(void*)l, 16, 0, 0);
}

// ---------------- small utility kernels ----------------

__global__ void zero_stats_k(float* __restrict__ stats) {
  int t = blockIdx.x * 256 + threadIdx.x;
  if (t < 2048) stats[t] = 0.f;
}

// features [B][128][N] -> x0b[b][n][0:128]
__global__ void transpose_x0_k(const float* __restrict__ feat, float* __restrict__ x0b) {
  __shared__ float tile[32][33];
  int b = blockIdx.z;
  int n0 = blockIdx.x * 32, c0 = blockIdx.y * 32;
  int tx = threadIdx.x;
  for (int ty = threadIdx.y; ty < 32; ty += 8)
    tile[ty][tx] = feat[((long)b * CH + c0 + ty) * NPTS + n0 + tx];
  __syncthreads();
  for (int ty = threadIdx.y; ty < 32; ty += 8)
    x0b[((long)b * NPTS + n0 + ty) * 128 + c0 + tx] = tile[tx][ty];
}

__global__ void prep_w_k(const float* __restrict__ W1, const float* __restrict__ W2,
                         float* __restrict__ Wm1, float* __restrict__ Wm2) {
  int t = blockIdx.x * 256 + threadIdx.x;
  if (t < 256 * 128) {
    int r = t >> 7, k = t & 127;
    Wm1[t] = (r < 128) ? (W1[r * 256 + k] - W1[r * 256 + 128 + k])
                       : W1[(r - 128) * 256 + 128 + k];
  }
  if (t < 512 * 128) {
    int r = t >> 7, k = t & 127;
    Wm2[t] = (r < 256) ? (W2[r * 256 + k] - W2[r * 256 + 128 + k])
                       : W2[(r - 256) * 256 + 128 + k];
  }
}

// sums (sum, sumsq) -> (scale, bias) per (b, col):  z = y*scale + bias
__global__ void finalize_scb_k(const float* __restrict__ stats, float2* __restrict__ scb,
                               int count, float cinv) {
  int t = blockIdx.x * 256 + threadIdx.x;
  if (t < count) {
    float mean = stats[t * 2] * cinv;
    float var = stats[t * 2 + 1] * cinv - mean * mean;
    float inv = rsqrtf(var + EPSI);
    scb[t] = make_float2(inv, -mean * inv);
  }
}

// ---------------- KNN ----------------
__global__ void knn_prep_k(const float* __restrict__ coords, float4* __restrict__ pts) {
  int b = blockIdx.y;
  int i = blockIdx.x * 256 + threadIdx.x;
  const float* cb = coords + (long)b * 3 * NPTS;
  float x = cb[i], y = cb[NPTS + i], z = cb[2 * NPTS + i];
  float sq = __fadd_rn(__fadd_rn(__fmul_rn(x, x), __fmul_rn(y, y)), __fmul_rn(z, z));
  pts[(long)b * NPTS + i] = make_float4(x, y, z, sq);
}

#define DIST(pi, pj, d2)                                                          \
  float dot = __fadd_rn(__fadd_rn(__fmul_rn((pi).x, (pj).x), __fmul_rn((pi).y, (pj).y)), \
                        __fmul_rn((pi).z, (pj).z));                               \
  float d2 = __fsub_rn(__fadd_rn((pi).w, (pj).w), __fmul_rn(2.0f, dot));

// Stable predicated insertion into ascending (d, id) list; ties keep earlier insert.
#define KNN_INSERT(d2v, jv)                                              \
  if ((d2v) < d[K17 - 1]) {                                              \
    _Pragma("unroll")                                                    \
    for (int s = K17 - 1; s > 0; --s) {                                  \
      if ((d2v) < d[s - 1]) { d[s] = d[s - 1]; id[s] = id[s - 1]; }      \
      else if ((d2v) < d[s]) { d[s] = (d2v); id[s] = (jv); }             \
    }                                                                    \
    if ((d2v) < d[0]) { d[0] = (d2v); id[0] = (jv); }                    \
  }

// Phase A: 32 sub-threads per point; sub s keeps top-2 of sample candidates
// j in [s*64, s*64+64) (sample = first 2048 points).
__global__ __launch_bounds__(256) void knn_phaseA_k(const float4* __restrict__ pts,
                                                    float2* __restrict__ pa) {
  int b = blockIdx.y;
  int ib = blockIdx.x & 127;
  int sg = blockIdx.x >> 7;          // 0..7
  int i = ib * 64 + (threadIdx.x & 63);
  int sub = sg * 4 + (threadIdx.x >> 6);   // 0..31
  const float4* P = pts + (long)b * NPTS;
  float4 pi = P[i];
  float d0 = BIGF, d1 = BIGF;
  int i0 = 0x7fffffff, i1 = 0x7fffffff;
  int j0 = sub * 64;
  for (int jj = 0; jj < 64; ++jj) {
    float4 pj = P[j0 + jj];
    DIST(pi, pj, d2)
    if (d2 < d1) {
      if (d2 < d0) { d1 = d0; i1 = i0; d0 = d2; i0 = j0 + jj; }
      else { d1 = d2; i1 = j0 + jj; }
    }
  }
  long base = (((long)b * NPTS + i) * 32 + sub) * 2;
  pa[base] = make_float2(d0, __int_as_float(i0));
  pa[base + 1] = make_float2(d1, __int_as_float(i1));
}

// Merge 32x2 partials -> tau = 17th smallest of the 64 sample distances
__global__ __launch_bounds__(256) void knn_mergeA_k(const float2* __restrict__ pa,
                                                    float* __restrict__ tau) {
  int b = blockIdx.y;
  int i = blockIdx.x * 256 + threadIdx.x;
  float d[K17]; int id[K17];
#pragma unroll
  for (int s = 0; s < K17; ++s) { d[s] = BIGF; id[s] = 0x7fffffff; }
  long base = ((long)b * NPTS + i) * 64;
  for (int c = 0; c < 64; ++c) {
    float2 v = pa[base + c];
    if (v.x < d[K17 - 1]) {
      int j = __float_as_int(v.y);
      KNN_INSERT(v.x, j);
    }
  }
  tau[(long)b * NPTS + i] = d[K17 - 1];
}

// Phase B: per (i, chunk) thread, append all candidates with d2 <= tau_i.
__global__ __launch_bounds__(256) void knn_filter_k(const float4* __restrict__ pts,
                                                    const float* __restrict__ tau,
                                                    float2* __restrict__ surv,
                                                    int* __restrict__ counts) {
  int b = blockIdx.z;
  int i = blockIdx.x * 256 + threadIdx.x;
  int chunk = blockIdx.y;
  const float4* P = pts + (long)b * NPTS;
  float4 pi = P[i];
  float t = tau[(long)b * NPTS + i];
  long sbase = (((long)b * NPTS + i) * NCH + chunk) * SCAP;
  int cnt = 0;
  int j0 = chunk * CHSZ;
#pragma unroll 2
  for (int jj = 0; jj < CHSZ; ++jj) {
    float4 pj = P[j0 + jj];
    DIST(pi, pj, d2)
    if (d2 <= t) {
      if (cnt < SCAP) surv[sbase + cnt] = make_float2(d2, __int_as_float(j0 + jj));
      cnt++;
    }
  }
  counts[((long)b * NPTS + i) * NCH + chunk] = cnt;
}

// Fused Merge-B: block = 32 points x 8 subs, each sub merges 4 chunks into a
// register top-17, 3-level LDS insert-merge tree.
__global__ __launch_bounds__(256) void knn_mergeB_k(const float2* __restrict__ surv,
                                                    const int* __restrict__ counts,
                                                    const float4* __restrict__ pts,
                                                    int* __restrict__ idxo) {
  __shared__ float2 lds[8][K17][32];
  int b = blockIdx.y;
  int pl = threadIdx.x & 31;
  int sub = threadIdx.x >> 5;
  int i = blockIdx.x * 32 + pl;
  const float4* P = pts + (long)b * NPTS;
  float4 pi = P[i];
  float d[K17]; int id[K17];
#pragma unroll
  for (int s = 0; s < K17; ++s) { d[s] = BIGF; id[s] = 0x7fffffff; }
  long cbase = ((long)b * NPTS + i) * NCH;
  int4 c4 = *(const int4*)(counts + cbase + sub * 4);
  int cnt4[4] = {c4.x, c4.y, c4.z, c4.w};
#pragma unroll
  for (int q = 0; q < 4; ++q) {
    int c = sub * 4 + q;
    int cnt = cnt4[q];
    if (cnt > SCAP) {
      int j0 = c * CHSZ;
      for (int jj = 0; jj < CHSZ; ++jj) {
        float4 pj = P[j0 + jj];
        DIST(pi, pj, d2)
        KNN_INSERT(d2, j0 + jj);
      }
    } else {
      long sb = (cbase + c) * SCAP;
      for (int p = 0; p < cnt; p += 2) {
        float4 v2 = *(const float4*)(surv + sb + p);
        if (v2.x < d[K17 - 1]) {
          int j = __float_as_int(v2.y);
          KNN_INSERT(v2.x, j);
        }
        if (p + 1 < cnt && v2.z < d[K17 - 1]) {
          int j = __float_as_int(v2.w);
          KNN_INSERT(v2.z, j);
        }
      }
    }
  }
#pragma unroll
  for (int s = 0; s < K17; ++s) lds[sub][s][pl] = make_float2(d[s], __int_as_float(id[s]));
  __syncthreads();
  if ((sub & 1) == 0) {
#pragma unroll
    for (int s = 0; s < K17; ++s) {
      float2 v = lds[sub + 1][s][pl];
      if (v.x < d[K17 - 1]) {
        int j = __float_as_int(v.y);
        KNN_INSERT(v.x, j);
      }
    }
  }
  __syncthreads();
  if ((sub & 1) == 0) {
#pragma unroll
    for (int s = 0; s < K17; ++s) lds[sub >> 1][s][pl] = make_float2(d[s], __int_as_float(id[s]));
  }
  __syncthreads();
  if (sub < 2) {
#pragma unroll
    for (int s = 0; s < K17; ++s) {
      float2 v = lds[2 * sub][s][pl];
      d[s] = v.x; id[s] = __float_as_int(v.y);
    }
#pragma unroll
    for (int s = 0; s < K17; ++s) {
      float2 v = lds[2 * sub + 1][s][pl];
      if (v.x < d[K17 - 1]) {
        int j = __float_as_int(v.y);
        KNN_INSERT(v.x, j);
      }
    }
  }
  __syncthreads();
  if (sub < 2) {
#pragma unroll
    for (int s = 0; s < K17; ++s) lds[sub][s][pl] = make_float2(d[s], __int_as_float(id[s]));
  }
  __syncthreads();
  if (sub == 0) {
#pragma unroll
    for (int s = 0; s < K17; ++s) {
      float2 v = lds[0][s][pl];
      d[s] = v.x; id[s] = __float_as_int(v.y);
    }
#pragma unroll
    for (int s = 0; s < K17; ++s) {
      float2 v = lds[1][s][pl];
      if (v.x < d[K17 - 1]) {
        int j = __float_as_int(v.y);
        KNN_INSERT(v.x, j);
      }
    }
    long ob = ((long)b * NPTS + i) * KNN;
#pragma unroll
    for (int s = 1; s < K17; ++s) idxo[ob + s - 1] = id[s];
  }
}

// ---------------- GEMM: Out[b][n][m] = sum_k X[b][n][k] * W[m][k] ----------------
#define GBN 128
#define GBM 64
#define GBK 32
__global__ __launch_bounds__(256) void gemm_xt_k(const float* __restrict__ X, int sx, long xbs,
                                                 const float* __restrict__ W, int K,
                                                 float* __restrict__ Out, int so, long obs) {
  __shared__ float Xs[GBK][GBN + 4];
  __shared__ float Ws[GBK][GBM + 4];
  int b = blockIdx.z;
  const float* Xb = X + (long)b * xbs;
  float* Ob = Out + (long)b * obs;
  int n0 = blockIdx.x * GBN, m0 = blockIdx.y * GBM;
  int tx = threadIdx.x, ty = threadIdx.y;
  int tid = ty * 16 + tx;
  float acc[8][4];
#pragma unroll
  for (int i = 0; i < 8; ++i)
#pragma unroll
    for (int j = 0; j < 4; ++j) acc[i][j] = 0.f;

  for (int k0 = 0; k0 < K; k0 += GBK) {
#pragma unroll
    for (int i = 0; i < 4; ++i) {
      int q = tid + i * 256;
      int r = q >> 3, kq = (q & 7) * 4;
      const float4 v = *(const float4*)(Xb + (long)(n0 + r) * sx + k0 + kq);
      Xs[kq][r] = v.x; Xs[kq + 1][r] = v.y; Xs[kq + 2][r] = v.z; Xs[kq + 3][r] = v.w;
    }
#pragma unroll
    for (int i = 0; i < 2; ++i) {
      int q = tid + i * 256;
      int r = q >> 3, kq = (q & 7) * 4;
      const float4 v = *(const float4*)(W + (long)(m0 + r) * K + k0 + kq);
      Ws[kq][r] = v.x; Ws[kq + 1][r] = v.y; Ws[kq + 2][r] = v.z; Ws[kq + 3][r] = v.w;
    }
    __syncthreads();
#pragma unroll
    for (int kk = 0; kk < GBK; ++kk) {
      float4 w4 = *(const float4*)&Ws[kk][tx * 4];
      float4 xa = *(const float4*)&Xs[kk][ty * 8];
      float4 xb4 = *(const float4*)&Xs[kk][ty * 8 + 4];
      float xs[8] = {xa.x, xa.y, xa.z, xa.w, xb4.x, xb4.y, xb4.z, xb4.w};
      float wv[4] = {w4.x, w4.y, w4.z, w4.w};
#pragma unroll
      for (int i = 0; i < 8; ++i)
#pragma unroll
        for (int j = 0; j < 4; ++j) acc[i][j] = fmaf(xs[i], wv[j], acc[i][j]);
    }
    __syncthreads();
  }
#pragma unroll
  for (int i = 0; i < 8; ++i) {
    float4 v = make_float4(acc[i][0], acc[i][1], acc[i][2], acc[i][3]);
    *(float4*)(Ob + (long)(n0 + ty * 8 + i) * so + m0 + tx * 4) = v;
  }
}

#define AFFLK4(v, a0, a1, a2, a3)                              \
  v.x = fmaf(v.x, a0.x, a0.y); v.x = fmaxf(v.x, SLOPE * v.x);  \
  v.y = fmaf(v.y, a1.x, a1.y); v.y = fmaxf(v.y, SLOPE * v.y);  \
  v.z = fmaf(v.z, a2.x, a2.y); v.z = fmaxf(v.z, SLOPE * v.z);  \
  v.w = fmaf(v.w, a3.x, a3.y); v.w = fmaxf(v.w, SLOPE * v.w);

// stage-3 GEMM: X = leaky(affine(ym1)) applied during staging. K=128, X stride 128.
__global__ __launch_bounds__(256) void gemm_aff_k(const float* __restrict__ X,
                                                  const float2* __restrict__ scb,
                                                  const float* __restrict__ W,
                                                  float* __restrict__ Out, int so, long obs) {
  __shared__ float Xs[GBK][GBN + 4];
  __shared__ float Ws[GBK][GBM + 4];
  int b = blockIdx.z;
  const float* Xb = X + (long)b * NPTS * 128;
  const float2* sc = scb + b * 128;
  float* Ob = Out + (long)b * obs;
  int n0 = blockIdx.x * GBN, m0 = blockIdx.y * GBM;
  int tx = threadIdx.x, ty = threadIdx.y;
  int tid = ty * 16 + tx;
  float acc[8][4];
#pragma unroll
  for (int i = 0; i < 8; ++i)
#pragma unroll
    for (int j = 0; j < 4; ++j) acc[i][j] = 0.f;

  for (int k0 = 0; k0 < 128; k0 += GBK) {
#pragma unroll
    for (int i = 0; i < 4; ++i) {
      int q = tid + i * 256;
      int r = q >> 3, kq = (q & 7) * 4;
      float4 v = *(const float4*)(Xb + (long)(n0 + r) * 128 + k0 + kq);
      float2 a0 = sc[k0 + kq], a1 = sc[k0 + kq + 1], a2 = sc[k0 + kq + 2], a3 = sc[k0 + kq + 3];
      AFFLK4(v, a0, a1, a2, a3)
      Xs[kq][r] = v.x; Xs[kq + 1][r] = v.y; Xs[kq + 2][r] = v.z; Xs[kq + 3][r] = v.w;
    }
#pragma unroll
    for (int i = 0; i < 2; ++i) {
      int q = tid + i * 256;
      int r = q >> 3, kq = (q & 7) * 4;
      const float4 v = *(const float4*)(W + (long)(m0 + r) * 128 + k0 + kq);
      Ws[kq][r] = v.x; Ws[kq + 1][r] = v.y; Ws[kq + 2][r] = v.z; Ws[kq + 3][r] = v.w;
    }
    __syncthreads();
#pragma unroll
    for (int kk = 0; kk < GBK; ++kk) {
      float4 w4 = *(const float4*)&Ws[kk][tx * 4];
      float4 xa = *(const float4*)&Xs[kk][ty * 8];
      float4 xb4 = *(const float4*)&Xs[kk][ty * 8 + 4];
      float xs[8] = {xa.x, xa.y, xa.z, xa.w, xb4.x, xb4.y, xb4.z, xb4.w};
      float wv[4] = {w4.x, w4.y, w4.z, w4.w};
#pragma unroll
      for (int i = 0; i < 8; ++i)
#pragma unroll
        for (int j = 0; j < 4; ++j) acc[i][j] = fmaf(xs[i], wv[j], acc[i][j]);
    }
    __syncthreads();
  }
#pragma unroll
  for (int i = 0; i < 8; ++i) {
    float4 v = make_float4(acc[i][0], acc[i][1], acc[i][2], acc[i][3]);
    *(float4*)(Ob + (long)(n0 + ty * 8 + i) * so + m0 + tx * 4) = v;
  }
}

// stage-4 GEMM: 128n x 64m tile + split-K 2-way (round-7 proven: 512 blocks =
// 2 blocks/CU so staging/barriers of one block overlap compute of the other).
// k-half 0 = x0b + ym1; k-half 1 = ym2 (segment-aligned split).
__global__ __launch_bounds__(256) void gemm_cat_k(const float* __restrict__ x0b,
                                                  const float* __restrict__ ym1,
                                                  const float* __restrict__ ym2,
                                                  const float2* __restrict__ scb1,
                                                  const float2* __restrict__ scb2,
                                                  const float* __restrict__ W,
                                                  float* __restrict__ OutA,
                                                  float* __restrict__ OutB) {
  __shared__ float Xs[GBK][GBN + 4];
  __shared__ float Ws[GBK][GBM + 4];
  int b = blockIdx.z;
  int mt = blockIdx.y & 1;
  int kh = blockIdx.y >> 1;
  float* Ob = (kh ? OutB : OutA) + (long)b * NPTS * 128;
  int n0 = blockIdx.x * GBN, m0 = mt * GBM;
  int tx = threadIdx.x, ty = threadIdx.y;
  int tid = ty * 16 + tx;
  float acc[8][4];
#pragma unroll
  for (int i = 0; i < 8; ++i)
#pragma unroll
    for (int j = 0; j < 4; ++j) acc[i][j] = 0.f;

  for (int ks = 0; ks < 8; ++ks) {
    int k0 = kh * 256 + ks * GBK;
    const float* Xb; long st_; const float2* sc_; int cb_;
    if (k0 < 128)      { Xb = x0b + (long)b * NPTS * 128; st_ = 128; sc_ = nullptr;        cb_ = 0; }
    else if (k0 < 256) { Xb = ym1 + (long)b * NPTS * 128; st_ = 128; sc_ = scb1 + b * 128; cb_ = 128; }
    else               { Xb = ym2 + (long)b * NPTS * 256; st_ = 256; sc_ = scb2 + b * 256; cb_ = 256; }
    int kl = k0 - cb_;
#pragma unroll
    for (int i = 0; i < 4; ++i) {
      int q = tid + i * 256;
      int r = q >> 3, kq = (q & 7) * 4;
      float4 v = *(const float4*)(Xb + (long)(n0 + r) * st_ + kl + kq);
      if (sc_) {
        float2 a0 = sc_[kl + kq], a1 = sc_[kl + kq + 1], a2 = sc_[kl + kq + 2], a3 = sc_[kl + kq + 3];
        AFFLK4(v, a0, a1, a2, a3)
      }
      Xs[kq][r] = v.x; Xs[kq + 1][r] = v.y; Xs[kq + 2][r] = v.z; Xs[kq + 3][r] = v.w;
    }
#pragma unroll
    for (int i = 0; i < 2; ++i) {
      int q = tid + i * 256;
      int r = q >> 3, kq = (q & 7) * 4;
      const float4 v = *(const float4*)(W + (long)(m0 + r) * 512 + k0 + kq);
      Ws[kq][r] = v.x; Ws[kq + 1][r] = v.y; Ws[kq + 2][r] = v.z; Ws[kq + 3][r] = v.w;
    }
    __syncthreads();
#pragma unroll
    for (int kk = 0; kk < GBK; ++kk) {
      float4 w4 = *(const float4*)&Ws[kk][tx * 4];
      float4 xa = *(const float4*)&Xs[kk][ty * 8];
      float4 xb4 = *(const float4*)&Xs[kk][ty * 8 + 4];
      float xs[8] = {xa.x, xa.y, xa.z, xa.w, xb4.x, xb4.y, xb4.z, xb4.w};
      float wv[4] = {w4.x, w4.y, w4.z, w4.w};
#pragma unroll
      for (int i = 0; i < 8; ++i)
#pragma unroll
        for (int j = 0; j < 4; ++j) acc[i][j] = fmaf(xs[i], wv[j], acc[i][j]);
    }
    __syncthreads();
  }
#pragma unroll
  for (int i = 0; i < 8; ++i) {
    float4 v = make_float4(acc[i][0], acc[i][1], acc[i][2], acc[i][3]);
    *(float4*)(Ob + (long)(n0 + ty * 8 + i) * 128 + m0 + tx * 4) = v;
  }
}

// ---------------- edge (r12 LDS-DMA + ROUND-13 counted-vmcnt smoothing) -------
// y = u[n] + v[idx[n,k]]; max over k + channel sum/sumsq.
// Grid/layout LOAD-BEARING (PPB=32, 1024 blocks, (b,ct) in blk bits 1-2).
// r12 (65.4us, LDS 32768 proof): 8-deep DMA with vmcnt(0) sawtooth (8->0).
// r13: T4 counted-vmcnt — 4-slot half-groups A=slots0-3, B=slots4-7, issue/
// consume interleaved so outstanding oscillates 8->4->8->4, never 0 mid-iter.
// vmcnt(4) is always "all but the just-issued group retired" — correct
// regardless of older stray ops (u load / ym store are older, retire first).
// Consumption order k=0..15 unchanged -> bit-identical. Same LDS/VGPR/grid.
// Null result (+/-1.5us) => per-CU miss-service cap binding => ROOFLINE.
template <int CTILE, int PPB>
__global__ __launch_bounds__(256) void edge_max_t(const float* __restrict__ uv, int S, int voff,
                                                  int Cout, const int* __restrict__ idx,
                                                  float* __restrict__ ymax,
                                                  float* __restrict__ stats) {
  constexpr int CG = CTILE / 4;     // channel-groups (threads per point-row)
  constexpr int PSL = 256 / CG;     // point-slots per block
  __shared__ float4 kb[4 * 8 * 64]; // 32KB: [wave][kslot 0..7][lane] float4
  int blk = blockIdx.x;
  int c = (blk & 7) >> 1;           // combo 0..3
  int b = c >> 1;                   // batch
  int ct = c & 1;                   // channel tile
  int pblk = ((blk >> 3) << 1) | (blk & 1);
  int ch0 = ct * CTILE;
  const float* uvb = uv + (long)b * NPTS * S;
  const int* idxb = idx + (long)b * NPTS * KNN;
  float* ymb = ymax + (long)b * NPTS * Cout;
  int cg = threadIdx.x & (CG - 1);
  int ps = threadIdx.x / CG;
  int n0 = pblk * PPB;
  int wid = threadIdx.x >> 6;
  int lane = threadIdx.x & 63;
  float4* kwb = kb + wid * 8 * 64;  // this wave's 8 x 64-lane slots
  const float* vb = uvb + voff + ch0 + 4 * cg;
  float4 s = make_float4(0.f, 0.f, 0.f, 0.f);
  float4 s2 = make_float4(0.f, 0.f, 0.f, 0.f);

#define CONSUME4(kbase, sbase)                                               \
  _Pragma("unroll")                                                          \
  for (int k = 0; k < 4; ++k) {                                              \
    float4 v = kwb[((sbase) + k) * 64 + lane];                               \
    float yx = u.x + v.x, yy = u.y + v.y, yz = u.z + v.z, yw = u.w + v.w;    \
    mx.x = fmaxf(mx.x, yx); mx.y = fmaxf(mx.y, yy);                          \
    mx.z = fmaxf(mx.z, yz); mx.w = fmaxf(mx.w, yw);                          \
    s.x += yx; s.y += yy; s.z += yz; s.w += yw;                              \
    s2.x = fmaf(yx, yx, s2.x); s2.y = fmaf(yy, yy, s2.y);                    \
    s2.z = fmaf(yz, yz, s2.z); s2.w = fmaf(yw, yw, s2.w);                    \
  }

  for (int p = ps; p < PPB; p += PSL) {
    int n = n0 + p;
    const int* ip = idxb + n * KNN;
    int4 ia = *(const int4*)(ip);
    int4 ib4 = *(const int4*)(ip + 4);
    int4 ic = *(const int4*)(ip + 8);
    int4 id4 = *(const int4*)(ip + 12);
    int mi[KNN] = {ia.x, ia.y, ia.z, ia.w, ib4.x, ib4.y, ib4.z, ib4.w,
                   ic.x, ic.y, ic.z, ic.w, id4.x, id4.y, id4.z, id4.w};
    float4 u = *(const float4*)(uvb + (long)n * S + ch0 + 4 * cg);
    float4 mx = make_float4(-INFINITY, -INFINITY, -INFINITY, -INFINITY);
    // issue A1 (k0-3 -> slots0-3) and B1 (k4-7 -> slots4-7): 8 in flight
#pragma unroll
    for (int k = 0; k < 8; ++k)
      gload_lds16(vb + (long)mi[k] * S, kwb + k * 64);
    asm volatile("s_waitcnt vmcnt(4)" ::: "memory");   // A1 landed (B1 in flight)
    __builtin_amdgcn_sched_barrier(0);
    CONSUME4(0, 0)                                     // k0-3
    asm volatile("s_waitcnt lgkmcnt(0)" ::: "memory"); // slot0-3 reads done
    __builtin_amdgcn_sched_barrier(0);
#pragma unroll
    for (int k = 8; k < 12; ++k)                       // issue A2 -> slots0-3
      gload_lds16(vb + (long)mi[k] * S, kwb + (k - 8) * 64);
    asm volatile("s_waitcnt vmcnt(4)" ::: "memory");   // B1 landed (A2 in flight)
    __builtin_amdgcn_sched_barrier(0);
    CONSUME4(4, 4)                                     // k4-7
    asm volatile("s_waitcnt lgkmcnt(0)" ::: "memory"); // slot4-7 reads done
    __builtin_amdgcn_sched_barrier(0);
#pragma unroll
    for (int k = 12; k < 16; ++k)                      // issue B2 -> slots4-7
      gload_lds16(vb + (long)mi[k] * S, kwb + (k - 8) * 64);
    asm volatile("s_waitcnt vmcnt(4)" ::: "memory");   // A2 landed (B2 in flight)
    __builtin_amdgcn_sched_barrier(0);
    CONSUME4(8, 0)                                     // k8-11
    asm volatile("s_waitcnt lgkmcnt(0)" ::: "memory");
    __builtin_amdgcn_sched_barrier(0);
    asm volatile("s_waitcnt vmcnt(0)" ::: "memory");   // B2 landed
    __builtin_amdgcn_sched_barrier(0);
    CONSUME4(12, 4)                                    // k12-15
    *(float4*)(ymb + (long)n * Cout + ch0 + 4 * cg) = mx;
    asm volatile("s_waitcnt lgkmcnt(0)" ::: "memory"); // drain before slot reuse
    __builtin_amdgcn_sched_barrier(0);
  }
#undef CONSUME4
  // all waves' DMAs drained -> safe to alias kb as stats scratch
  __syncthreads();
  float* ls0 = (float*)kb;          // [256][4]
  float* ls1 = ls0 + 1024;          // [256][4]
  int t = threadIdx.x;
  ls0[t * 4 + 0] = s.x; ls0[t * 4 + 1] = s.y; ls0[t * 4 + 2] = s.z; ls0[t * 4 + 3] = s.w;
  ls1[t * 4 + 0] = s2.x; ls1[t * 4 + 1] = s2.y; ls1[t * 4 + 2] = s2.z; ls1[t * 4 + 3] = s2.w;
  __syncthreads();
  if (ps == 0) {
#pragma unroll
    for (int j = 1; j < PSL; ++j) {
      int q = j * CG + cg;
      s.x += ls0[q * 4 + 0]; s.y += ls0[q * 4 + 1]; s.z += ls0[q * 4 + 2]; s.w += ls0[q * 4 + 3];
      s2.x += ls1[q * 4 + 0]; s2.y += ls1[q * 4 + 1]; s2.z += ls1[q * 4 + 2]; s2.w += ls1[q * 4 + 3];
    }
    float* st = stats + ((long)b * Cout + ch0 + 4 * cg) * 2;
    atomicAdd(&st[0], s.x); atomicAdd(&st[1], s2.x);
    atomicAdd(&st[2], s.y); atomicAdd(&st[3], s2.y);
    atomicAdd(&st[4], s.z); atomicAdd(&st[5], s2.z);
    atomicAdd(&st[6], s.w); atomicAdd(&st[7], s2.w);
  }
}

// sum split-K halves -> y4; per-column (sum, sumsq) -> stats
__global__ void colstats2_k(float* __restrict__ y4, const float* __restrict__ y4b,
                            float* __restrict__ stats) {
  int b = blockIdx.y;
  int o = threadIdx.x & 127, slot = threadIdx.x >> 7;
  int n0 = blockIdx.x * 64;
  float s = 0.f, s2 = 0.f;
  for (int p = slot; p < 64; p += 2) {
    long off = ((long)b * NPTS + n0 + p) * 128 + o;
    float y = y4[off] + y4b[off];
    y4[off] = y;
    s += y;
    s2 = fmaf(y, y, s2);
  }
  float* st = stats + ((long)b * 128 + o) * 2;
  atomicAdd(&st[0], s);
  atomicAdd(&st[1], s2);
}

__global__ void final_k(const float* __restrict__ y3, const float* __restrict__ stats,
                        float* __restrict__ out) {
  __shared__ float tile[32][33];
  int b = blockIdx.z;
  int n0 = blockIdx.x * 32, o0 = blockIdx.y * 32;
  int tx = threadIdx.x;
  for (int ty = threadIdx.y; ty < 32; ty += 8) {
    int o = o0 + tx;
    const float* st = stats + ((long)b * 128 + o) * 2;
    float mean = st[0] * (1.f / 8192.f);
    float var = st[1] * (1.f / 8192.f) - mean * mean;
    float inv = rsqrtf(var + EPSI);
    float y = y3[((long)b * NPTS + n0 + ty) * 128 + o];
    float z = (y - mean) * inv;
    tile[ty][tx] = z >= 0.f ? z : SLOPE * z;
  }
  __syncthreads();
  for (int ty = threadIdx.y; ty < 32; ty += 8)
    out[((long)b * CH + o0 + ty) * NPTS + n0 + tx] = tile[tx][ty];
}

// ---------------- launch ----------------
extern "C" void kernel_launch(void* const* d_in, const int* in_sizes, int n_in,
                              void* d_out, int out_size, void* d_ws, size_t ws_size,
                              hipStream_t stream) {
  const float* coords = (const float*)d_in[0];
  const float* features = (const float*)d_in[1];
  const float* W1 = (const float*)d_in[2];
  const float* W2 = (const float*)d_in[3];
  const float* W3 = (const float*)d_in[4];
  float* out = (float*)d_out;
  char* ws = (char*)d_ws;

  int* idx = (int*)(ws + OFF_IDX);
  float* x0b = (float*)(ws + OFF_X0B);
  float* ym1 = (float*)(ws + OFF_YM1);
  float* ym2 = (float*)(ws + OFF_YM2);
  float* uv = (float*)(ws + OFF_UV);
  float* y4 = (float*)(ws + OFF_Y4);
  float2* surv = (float2*)(ws + OFF_SURV);
  float2* pa = (float2*)(ws + OFF_PA);
  int* counts = (int*)(ws + OFF_CNT);
  float* tau = (float*)(ws + OFF_TAU);
  float* wm1 = (float*)(ws + OFF_WM1);
  float* wm2 = (float*)(ws + OFF_WM2);
  float* stats = (float*)(ws + OFF_STATS);
  float2* scb1 = (float2*)(ws + OFF_SCB1);
  float2* scb2 = (float2*)(ws + OFF_SCB2);
  float4* pts4 = (float4*)(ws + OFF_PTS4);

  zero_stats_k<<<8, 256, 0, stream>>>(stats);
  // ---- KNN ----
  knn_prep_k<<<dim3(NPTS / 256, NB), 256, 0, stream>>>(coords, pts4);
  knn_phaseA_k<<<dim3(1024, NB), 256, 0, stream>>>(pts4, pa);
  knn_mergeA_k<<<dim3(NPTS / 256, NB), 256, 0, stream>>>(pa, tau);
  knn_filter_k<<<dim3(NPTS / 256, NCH, NB), 256, 0, stream>>>(pts4, tau, surv, counts);
  knn_mergeB_k<<<dim3(NPTS / 32, NB), 256, 0, stream>>>(surv, counts, pts4, idx);

  transpose_x0_k<<<dim3(NPTS / 32, CH / 32, NB), dim3(32, 8), 0, stream>>>(features, x0b);
  prep_w_k<<<256, 256, 0, stream>>>(W1, W2, wm1, wm2);

  // stage 2 (edge: 1024 blocks, PPB=32 — round-0 proven grid)
  gemm_xt_k<<<dim3(NPTS / GBN, 256 / GBM, NB), dim3(16, 16), 0, stream>>>(
      x0b, 128, (long)NPTS * 128, wm1, 128, uv, 256, (long)NPTS * 256);
  edge_max_t<64, 32><<<dim3(NPTS / 32 * 2 * NB), 256, 0, stream>>>(uv, 256, 128, 128, idx,
                                                                   ym1, stats);
  finalize_scb_k<<<1, 256, 0, stream>>>(stats, scb1, 256, 1.0f / 131072.0f);
  // stage 3
  gemm_aff_k<<<dim3(NPTS / GBN, 512 / GBM, NB), dim3(16, 16), 0, stream>>>(
      ym1, scb1, wm2, uv, 512, (long)NPTS * 512);
  edge_max_t<128, 32><<<dim3(NPTS / 32 * 2 * NB), 256, 0, stream>>>(uv, 512, 256, 256, idx,
                                                                    ym2, stats + 512);
  finalize_scb_k<<<2, 256, 0, stream>>>(stats + 512, scb2, 512, 1.0f / 131072.0f);
  // stage 4: 128x64 tile, split-K 2-way -> (64, 4, 2) = 512 blocks = 2/CU.
  gemm_cat_k<<<dim3(NPTS / GBN, 4, NB), dim3(16, 16), 0, stream>>>(
      x0b, ym1, ym2, scb1, scb2, W3, y4, uv);
  colstats2_k<<<dim3(NPTS / 64, NB), 256, 0, stream>>>(y4, uv, stats + 1536);
  final_k<<<dim3(NPTS / 32, CH / 32, NB), dim3(32, 8), 0, stream>>>(y4, stats + 1536, out);
}